// Round 4
// baseline (554.114 us; speedup 1.0000x reference)
//
#include <hip/hip_runtime.h>
#include <math.h>

// GatedCrossAttentionFusion on MI355X (gfx950), bf16 MFMA pipeline.
// B=16384, VD=2048, SD=1024, CD=512, H=256, HEADS=4, DH=64.
//
// Pipeline (all bf16 intermediates in ws):
//  K0 cvt_w     : fp32->bf16 weight conversion (Wv,Ws,Wc,in_w,out_w,g1w)
//  K1 gemm_ln   : {fv,fs,fc} @ W.T + bias -> LayerNorm -> stack (B*3,256) bf16
//  K2 gemm_qkv  : stack @ in_w.T + in_b -> qkv (B*3,768) bf16
//  K3 attn_k    : per-b 4-head 3x3 attention -> ctx (B*3,256) bf16
//  K4 outproj_k : ctx @ out_w.T + out_b + stack -> LN -> gating MLP -> fused+gates
//
// R0-R3 lesson: LDS-staged K-loops (any schedule: syncthreads, 1-deep dbuf,
// depth-2 counted-vmcnt) all pin gemm_ln at ~130us because the per-K-step
// workgroup barrier couples all waves to the slowest outstanding load; MLP
// collapses (~1.3MB in flight chip-wide). R4: K1/K2 main loops are BARRIER-FREE
// and LDS-FREE -- MFMA fragments load global->register directly (A frag = 8
// consecutive fp32 per lane, B frag = 16B per lane), depth-1 register prefetch,
// waves free-running. Raw s_barrier (no waitcnt drain) every 2 K-steps only to
// keep the 4 waves temporally aligned for L1 reuse of shared A bytes.

typedef unsigned short u16;
typedef __bf16 bf16x8 __attribute__((ext_vector_type(8)));
typedef float fx4 __attribute__((ext_vector_type(4)));

#define MFMA_BF16(A_, B_, C_) __builtin_amdgcn_mfma_f32_16x16x32_bf16((A_), (B_), (C_), 0, 0, 0)

__device__ __forceinline__ float bf2f(u16 s) {
    union { float f; unsigned u; } c; c.u = ((unsigned)s) << 16; return c.f;
}
__device__ __forceinline__ u16 f2bf(float f) {
    union { float f; unsigned u; } c; c.f = f;
    return (u16)((c.u + 0x7fffu + ((c.u >> 16) & 1u)) >> 16);
}
// a,b are packed bf16 pairs (little-endian: low u16 = even element)
__device__ __forceinline__ float bfpair_dot(unsigned a, unsigned b) {
    union { unsigned u; float f; } al, ah, bl, bh;
    al.u = a << 16; ah.u = a & 0xffff0000u;
    bl.u = b << 16; bh.u = b & 0xffff0000u;
    return al.f * bl.f + ah.f * bh.f;
}
__device__ __forceinline__ void gld16(void* l, const void* g) {
    __builtin_amdgcn_global_load_lds((const __attribute__((address_space(1))) void*)g,
                                     (__attribute__((address_space(3))) void*)l, 16, 0, 0);
}

// ---------------------------------------------------------------- K0: weights
__global__ __launch_bounds__(256) void cvt_w(const float* Wv, const float* Ws, const float* Wc,
                                             const float* inw, const float* outw, const float* g1w,
                                             u16* dst) {
    int idx = blockIdx.x * 256 + threadIdx.x;  // grid covers exactly 1228800
    const float* src; int rel;
    if      (idx <  524288) { src = Wv;   rel = idx; }
    else if (idx <  786432) { src = Ws;   rel = idx -  524288; }
    else if (idx <  917504) { src = Wc;   rel = idx -  786432; }
    else if (idx < 1114112) { src = inw;  rel = idx -  917504; }
    else if (idx < 1179648) { src = outw; rel = idx - 1114112; }
    else                    { src = g1w;  rel = idx - 1179648; }
    dst[idx] = f2bf(src[rel]);
}

// ------------------------------------------------- K1: input GEMM + LayerNorm
// BM=64, BN=256(=H), BK=32, 4 waves (wave w owns cols w*64..w*64+63; all waves
// share the same 64 A-rows -> L1 serves 3 of 4 reads). 1D grid of 768 blocks,
// longest-job-first. Main loop: direct global->register fragment loads, depth-1
// register prefetch (2-unrolled, static reg indexing), NO LDS, NO syncthreads.
__global__ __launch_bounds__(256, 2) void gemm_ln(
    const float* fv, const float* fs, const float* fc,
    const u16* wWv, const u16* wWs, const u16* wWc,
    const float* bv, const float* gv, const float* bev,
    const float* bs, const float* gs, const float* bes,
    const float* bc, const float* gc_, const float* bec,
    u16* stack) {
    __shared__ alignas(16) char smem[35328];
    u16* sC = (u16*)smem;                   // epilogue [64][256] bf16
    float* redS = (float*)(smem + 32768);   // [64][4]
    float* redQ = (float*)(smem + 33792);   // [64][4]
    float* mvS  = (float*)(smem + 34816);   // [64][2] mean,rstd

    int bid = blockIdx.x;
    int slot, mblk;
    if (bid < 256)      { slot = 0; mblk = bid; }
    else if (bid < 512) { slot = 1; mblk = bid - 256; }
    else                { slot = 2; mblk = bid - 512; }

    const float* A; const u16* W; const float* bias; const float* gg; const float* be; int K;
    if (slot == 0)      { A = fv; W = wWv; bias = bv; gg = gv;  be = bev; K = 2048; }
    else if (slot == 1) { A = fs; W = wWs; bias = bs; gg = gs;  be = bes; K = 1024; }
    else                { A = fc; W = wWc; bias = bc; gg = gc_; be = bec; K = 512;  }

    int t = threadIdx.x, wv = t >> 6, ln = t & 63, q = ln >> 4, l15 = ln & 15;
    int m0 = mblk * 64;

    // fragment base pointers (per lane)
    const float* aRow[4];
    #pragma unroll
    for (int mi = 0; mi < 4; ++mi)
        aRow[mi] = A + (size_t)(m0 + mi * 16 + l15) * K + q * 8;
    const u16* bCol[4];
    #pragma unroll
    for (int ni = 0; ni < 4; ++ni)
        bCol[ni] = W + (size_t)(wv * 64 + ni * 16 + l15) * K + q * 8;

    fx4 zero = {0.f, 0.f, 0.f, 0.f};
    fx4 acc[4][4];
    #pragma unroll
    for (int mi = 0; mi < 4; ++mi)
        #pragma unroll
        for (int ni = 0; ni < 4; ++ni) acc[mi][ni] = zero;

    float4 pa0[4][2], pa1[4][2];
    bf16x8 pb0[4], pb1[4];

#define LN_LOAD(A_, B_, kk)                                                \
    {                                                                      \
        _Pragma("unroll")                                                  \
        for (int mi_ = 0; mi_ < 4; ++mi_) {                                \
            A_[mi_][0] = *(const float4*)(aRow[mi_] + (kk) * 32);          \
            A_[mi_][1] = *(const float4*)(aRow[mi_] + (kk) * 32 + 4);      \
        }                                                                  \
        _Pragma("unroll")                                                  \
        for (int ni_ = 0; ni_ < 4; ++ni_)                                  \
            B_[ni_] = *(const bf16x8*)(bCol[ni_] + (kk) * 32);             \
    }

#define LN_COMP(A_, B_)                                                    \
    {                                                                      \
        bf16x8 af_[4];                                                     \
        _Pragma("unroll")                                                  \
        for (int mi_ = 0; mi_ < 4; ++mi_) {                                \
            af_[mi_][0] = (__bf16)A_[mi_][0].x;                            \
            af_[mi_][1] = (__bf16)A_[mi_][0].y;                            \
            af_[mi_][2] = (__bf16)A_[mi_][0].z;                            \
            af_[mi_][3] = (__bf16)A_[mi_][0].w;                            \
            af_[mi_][4] = (__bf16)A_[mi_][1].x;                            \
            af_[mi_][5] = (__bf16)A_[mi_][1].y;                            \
            af_[mi_][6] = (__bf16)A_[mi_][1].z;                            \
            af_[mi_][7] = (__bf16)A_[mi_][1].w;                            \
        }                                                                  \
        _Pragma("unroll")                                                  \
        for (int mi_ = 0; mi_ < 4; ++mi_)                                  \
            _Pragma("unroll")                                              \
            for (int ni_ = 0; ni_ < 4; ++ni_)                              \
                acc[mi_][ni_] = MFMA_BF16(af_[mi_], B_[ni_], acc[mi_][ni_]); \
    }

    int niter = K >> 5;   // 64 / 32 / 16 -- all even
    LN_LOAD(pa0, pb0, 0);
    for (int kt = 0; kt < niter; kt += 2) {
        LN_LOAD(pa1, pb1, kt + 1);
        LN_COMP(pa0, pb0);
        if (kt + 2 < niter) LN_LOAD(pa0, pb0, kt + 2);
        LN_COMP(pa1, pb1);
        __builtin_amdgcn_s_barrier();   // drift control only; no waitcnt drain
    }
#undef LN_LOAD
#undef LN_COMP

    // epilogue: bias, LN stats from registers, normalize, write bf16
    float biasv[4], gvv[4], bevv[4];
    #pragma unroll
    for (int ni = 0; ni < 4; ++ni) {
        int col = wv * 64 + ni * 16 + l15;
        biasv[ni] = bias[col]; gvv[ni] = gg[col]; bevv[ni] = be[col];
    }
    #pragma unroll
    for (int mi = 0; mi < 4; ++mi)
        #pragma unroll
        for (int ni = 0; ni < 4; ++ni)
            #pragma unroll
            for (int r = 0; r < 4; ++r) acc[mi][ni][r] += biasv[ni];
    #pragma unroll
    for (int mi = 0; mi < 4; ++mi) {
        #pragma unroll
        for (int r = 0; r < 4; ++r) {
            float s = 0.f, qq = 0.f;
            #pragma unroll
            for (int ni = 0; ni < 4; ++ni) { float x = acc[mi][ni][r]; s += x; qq += x * x; }
            #pragma unroll
            for (int m = 1; m < 16; m <<= 1) { s += __shfl_xor(s, m, 64); qq += __shfl_xor(qq, m, 64); }
            if (l15 == 0) { int rho = mi * 16 + q * 4 + r; redS[rho * 4 + wv] = s; redQ[rho * 4 + wv] = qq; }
        }
    }
    __syncthreads();
    if (t < 64) {
        float s = redS[t * 4] + redS[t * 4 + 1] + redS[t * 4 + 2] + redS[t * 4 + 3];
        float qq = redQ[t * 4] + redQ[t * 4 + 1] + redQ[t * 4 + 2] + redQ[t * 4 + 3];
        float mean = s * (1.f / 256.f);
        float var = qq * (1.f / 256.f) - mean * mean;
        mvS[t * 2] = mean; mvS[t * 2 + 1] = rsqrtf(var + 1e-5f);
    }
    __syncthreads();
    #pragma unroll
    for (int mi = 0; mi < 4; ++mi) {
        #pragma unroll
        for (int r = 0; r < 4; ++r) {
            int rho = mi * 16 + q * 4 + r;
            float mean = mvS[rho * 2], rstd = mvS[rho * 2 + 1];
            #pragma unroll
            for (int ni = 0; ni < 4; ++ni) {
                int col = wv * 64 + ni * 16 + l15;
                float x = (acc[mi][ni][r] - mean) * rstd * gvv[ni] + bevv[ni];
                sC[rho * 256 + col] = f2bf(x);
            }
        }
    }
    __syncthreads();
    u16* outp = stack + (size_t)m0 * 768 + slot * 256;
    #pragma unroll
    for (int it = 0; it < 8; ++it) {
        int idx = t + it * 256;
        int row = idx >> 5, c = idx & 31;
        uint4 v = *(const uint4*)(sC + row * 256 + c * 8);
        *(uint4*)(outp + (size_t)row * 768 + c * 8) = v;
    }
}

// ------------------------------------------------------ K2: qkv = stack@in_w.T
// M=49152, K=256, N=768. BM=128, BN=128, 4 waves in 2x2. Same barrier-free
// direct global->register fragment loads, depth-1 register prefetch.
__global__ __launch_bounds__(256, 2) void gemm_qkv(const u16* stack, const u16* W, const float* in_b,
                                                   u16* qkv) {
    __shared__ alignas(16) char smem[32768];
    u16* sC = (u16*)smem;            // epilogue [128][128]

    int t = threadIdx.x, wv = t >> 6, ln = t & 63, q = ln >> 4, l15 = ln & 15;
    int n0 = blockIdx.x * 128, m0 = blockIdx.y * 128;
    int wr = wv >> 1, wc = wv & 1;

    const u16* aRow[4];
    #pragma unroll
    for (int mi = 0; mi < 4; ++mi)
        aRow[mi] = stack + (size_t)(m0 + wr * 64 + mi * 16 + l15) * 256 + q * 8;
    const u16* bCol[4];
    #pragma unroll
    for (int ni = 0; ni < 4; ++ni)
        bCol[ni] = W + (size_t)(n0 + wc * 64 + ni * 16 + l15) * 256 + q * 8;

    fx4 zero = {0.f, 0.f, 0.f, 0.f};
    fx4 acc[4][4];
    #pragma unroll
    for (int mi = 0; mi < 4; ++mi)
        #pragma unroll
        for (int ni = 0; ni < 4; ++ni) acc[mi][ni] = zero;

    bf16x8 pa0[4], pa1[4], pb0[4], pb1[4];

#define QK_LOAD(A_, B_, kk)                                                \
    {                                                                      \
        _Pragma("unroll")                                                  \
        for (int mi_ = 0; mi_ < 4; ++mi_)                                  \
            A_[mi_] = *(const bf16x8*)(aRow[mi_] + (kk) * 32);             \
        _Pragma("unroll")                                                  \
        for (int ni_ = 0; ni_ < 4; ++ni_)                                  \
            B_[ni_] = *(const bf16x8*)(bCol[ni_] + (kk) * 32);             \
    }

#define QK_COMP(A_, B_)                                                    \
    {                                                                      \
        _Pragma("unroll")                                                  \
        for (int mi_ = 0; mi_ < 4; ++mi_)                                  \
            _Pragma("unroll")                                              \
            for (int ni_ = 0; ni_ < 4; ++ni_)                              \
                acc[mi_][ni_] = MFMA_BF16(A_[mi_], B_[ni_], acc[mi_][ni_]); \
    }

    QK_LOAD(pa0, pb0, 0);
    for (int kt = 0; kt < 8; kt += 2) {
        QK_LOAD(pa1, pb1, kt + 1);
        QK_COMP(pa0, pb0);
        if (kt + 2 < 8) QK_LOAD(pa0, pb0, kt + 2);
        QK_COMP(pa1, pb1);
        __builtin_amdgcn_s_barrier();   // drift control only
    }
#undef QK_LOAD
#undef QK_COMP

    __syncthreads();
    float biasv[4];
    #pragma unroll
    for (int ni = 0; ni < 4; ++ni) biasv[ni] = in_b[n0 + wc * 64 + ni * 16 + l15];
    #pragma unroll
    for (int mi = 0; mi < 4; ++mi)
        #pragma unroll
        for (int ni = 0; ni < 4; ++ni)
            #pragma unroll
            for (int r = 0; r < 4; ++r) {
                int rl = wr * 64 + mi * 16 + q * 4 + r;
                int cl = wc * 64 + ni * 16 + l15;
                sC[rl * 128 + cl] = f2bf(acc[mi][ni][r] + biasv[ni]);
            }
    __syncthreads();
    #pragma unroll
    for (int it = 0; it < 8; ++it) {
        int idx = t + it * 256;
        int row = idx >> 4, c = idx & 15;
        uint4 v = *(const uint4*)(sC + row * 128 + c * 8);
        *(uint4*)(qkv + (size_t)(m0 + row) * 768 + n0 + c * 8) = v;
    }
}

// ------------------------------------------------------------- K3: attention
// 8 b's per block. qkv row per (b,i): [q(256)|k(256)|v(256)].
__global__ __launch_bounds__(256) void attn_k(const u16* qkv, u16* ctx) {
    __shared__ alignas(16) char smem[38016];
    u16* qs = (u16*)smem;                 // 8*2304 bf16
    float* sS = (float*)(smem + 36864);   // 288 scores/probs: [b][h][i][j]

    int t = threadIdx.x, wv = t >> 6, ln = t & 63;
    size_t base = (size_t)blockIdx.x * 8 * 2304;
    #pragma unroll
    for (int i = 0; i < 9; ++i) {
        int d = wv * 576 + i * 64;
        gld16((char*)smem + (size_t)d * 16, qkv + base + (size_t)(d + ln) * 8);
    }
    __syncthreads();
    // scores: 288 items = 8b*4h*9(i,j)
    #pragma unroll
    for (int it = 0; it < 2; ++it) {
        int idx = t + it * 256;
        if (idx < 288) {
            int b = idx / 36, rem = idx % 36, h = rem / 9, pp = rem % 9, i = pp / 3, j = pp % 3;
            const u16* qp = qs + b * 2304 + i * 768 + h * 64;
            const u16* kp = qs + b * 2304 + j * 768 + 256 + h * 64;
            float acc = 0.f;
            #pragma unroll
            for (int c = 0; c < 8; ++c) {
                uint4 qa = *(const uint4*)(qp + c * 8);
                uint4 ka = *(const uint4*)(kp + c * 8);
                acc += bfpair_dot(qa.x, ka.x) + bfpair_dot(qa.y, ka.y) +
                       bfpair_dot(qa.z, ka.z) + bfpair_dot(qa.w, ka.w);
            }
            sS[idx] = acc * 0.125f;  // /sqrt(64)
        }
    }
    __syncthreads();
    if (t < 96) {  // softmax over j, t = b*12 + h*3 + i
        int b3 = t * 3;
        float s0 = sS[b3], s1 = sS[b3 + 1], s2 = sS[b3 + 2];
        float m = fmaxf(s0, fmaxf(s1, s2));
        float e0 = __expf(s0 - m), e1 = __expf(s1 - m), e2 = __expf(s2 - m);
        float inv = 1.f / (e0 + e1 + e2);
        sS[b3] = e0 * inv; sS[b3 + 1] = e1 * inv; sS[b3 + 2] = e2 * inv;
    }
    __syncthreads();
    // ctx: 768 items = 8b * 3i * 32 chunks-of-8
    #pragma unroll
    for (int it = 0; it < 3; ++it) {
        int idx = t + it * 256;
        int b = idx / 96, rem = idx % 96, i = rem / 32, c = rem & 31, h = c >> 3;
        int pbase = b * 36 + h * 9 + i * 3;
        float o[8];
        #pragma unroll
        for (int e = 0; e < 8; ++e) o[e] = 0.f;
        #pragma unroll
        for (int j = 0; j < 3; ++j) {
            float p = sS[pbase + j];
            uint4 va = *(const uint4*)(qs + b * 2304 + j * 768 + 512 + c * 8);
            unsigned uu[4] = {va.x, va.y, va.z, va.w};
            #pragma unroll
            for (int pr = 0; pr < 4; ++pr) {
                union { unsigned u; float f; } lo, hi;
                lo.u = uu[pr] << 16; hi.u = uu[pr] & 0xffff0000u;
                o[2 * pr]     += p * lo.f;
                o[2 * pr + 1] += p * hi.f;
            }
        }
        union { u16 us[8]; uint4 v; } pk;
        #pragma unroll
        for (int e = 0; e < 8; ++e) pk.us[e] = f2bf(o[e]);
        *(uint4*)(ctx + (size_t)(blockIdx.x * 8 + b) * 768 + i * 256 + c * 8) = pk.v;
    }
}

// -------------------- K4: out-proj + residual + LN + gating MLP + fused output
// BM=48 (16 b's), BN=256, K=256. region1: ctxA -> stackS -> rowBuf(attended,swizzled)
__global__ __launch_bounds__(256) void outproj_k(
    const u16* ctx, const u16* W, const float* out_b, const u16* stack,
    const float* gn, const float* gb, const u16* g1w, const float* g1b,
    const float* g2w, const float* g2b, float* outF, float* outG) {
    __shared__ alignas(16) char smem[40960];
    u16* r1 = (u16*)smem;                         // 24576B
    u16* sB = (u16*)(smem + 24576);               // 16384B (k-loop)
    float* redS = (float*)(smem + 24576);         // 48*4
    float* redQ = redS + 192;
    float* mvS = redQ + 192;                      // 48*2
    float* h1S = (float*)(smem + 26624);          // [16][64]
    float* lgS = (float*)(smem + 30720);          // 48 logits
    float* gateS = lgS + 48;                      // 48 gates

    int t = threadIdx.x, wv = t >> 6, ln = t & 63, q = ln >> 4, l15 = ln & 15;
    int gr0 = blockIdx.x * 48, b0 = blockIdx.x * 16;

    // stage full ctx tile [48][256] once, chunk pos p holds k-chunk p^(row&7)
    #pragma unroll
    for (int i = 0; i < 6; ++i) {
        int d = wv * 384 + i * 64 + ln;
        int row = d >> 5, p = d & 31;
        int kc = p ^ (row & 7);
        gld16((char*)r1 + (wv * 384 + i * 64) * 16, ctx + (size_t)(gr0 + row) * 256 + kc * 8);
    }
    __syncthreads();

    fx4 zero = {0.f, 0.f, 0.f, 0.f};
    fx4 acc[3][4];
    #pragma unroll
    for (int mi = 0; mi < 3; ++mi)
        #pragma unroll
        for (int ni = 0; ni < 4; ++ni) acc[mi][ni] = zero;

    for (int kt = 0; kt < 8; ++kt) {
        #pragma unroll
        for (int i = 0; i < 4; ++i) {
            int d = wv * 256 + i * 64 + ln;
            int n = d >> 2, p = d & 3;
            int kc = p ^ ((n >> 1) & 3);
            gld16((char*)sB + (wv * 256 + i * 64) * 16, W + (size_t)n * 256 + kt * 32 + kc * 8);
        }
        __syncthreads();
        bf16x8 af[3], bfr[4];
        #pragma unroll
        for (int mi = 0; mi < 3; ++mi) {
            int row = mi * 16 + l15;
            int ch = row * 32 + ((kt * 4 + q) ^ (row & 7));
            af[mi] = *(const bf16x8*)(r1 + ch * 8);
        }
        #pragma unroll
        for (int ni = 0; ni < 4; ++ni) {
            int n = wv * 64 + ni * 16 + l15;
            int ch = n * 4 + (q ^ ((n >> 1) & 3));
            bfr[ni] = *(const bf16x8*)(sB + ch * 8);
        }
        #pragma unroll
        for (int mi = 0; mi < 3; ++mi)
            #pragma unroll
            for (int ni = 0; ni < 4; ++ni)
                acc[mi][ni] = MFMA_BF16(af[mi], bfr[ni], acc[mi][ni]);
        __syncthreads();
    }

    // stage stack tile [48][256] (contiguous in global) into r1
    #pragma unroll
    for (int i = 0; i < 6; ++i) {
        int d = wv * 384 + i * 64 + ln;
        gld16((char*)r1 + (wv * 384 + i * 64) * 16, stack + (size_t)gr0 * 256 + (size_t)d * 8);
    }
    __syncthreads();

    float obv[4], gnv[4], gbv[4];
    #pragma unroll
    for (int ni = 0; ni < 4; ++ni) {
        int col = wv * 64 + ni * 16 + l15;
        obv[ni] = out_b[col]; gnv[ni] = gn[col]; gbv[ni] = gb[col];
    }
    #pragma unroll
    for (int mi = 0; mi < 3; ++mi)
        #pragma unroll
        for (int ni = 0; ni < 4; ++ni)
            #pragma unroll
            for (int r = 0; r < 4; ++r) {
                int rho = mi * 16 + q * 4 + r;
                int col = wv * 64 + ni * 16 + l15;
                acc[mi][ni][r] += obv[ni] + bf2f(r1[rho * 256 + col]);
            }
    // LN stats
    #pragma unroll
    for (int mi = 0; mi < 3; ++mi) {
        #pragma unroll
        for (int r = 0; r < 4; ++r) {
            float s = 0.f, qq = 0.f;
            #pragma unroll
            for (int ni = 0; ni < 4; ++ni) { float x = acc[mi][ni][r]; s += x; qq += x * x; }
            #pragma unroll
            for (int m = 1; m < 16; m <<= 1) { s += __shfl_xor(s, m, 64); qq += __shfl_xor(qq, m, 64); }
            if (l15 == 0) { int rho = mi * 16 + q * 4 + r; redS[rho * 4 + wv] = s; redQ[rho * 4 + wv] = qq; }
        }
    }
    __syncthreads();
    if (t < 48) {
        float s = redS[t * 4] + redS[t * 4 + 1] + redS[t * 4 + 2] + redS[t * 4 + 3];
        float qq = redQ[t * 4] + redQ[t * 4 + 1] + redQ[t * 4 + 2] + redQ[t * 4 + 3];
        float mean = s * (1.f / 256.f);
        float var = qq * (1.f / 256.f) - mean * mean;
        mvS[t * 2] = mean; mvS[t * 2 + 1] = rsqrtf(var + 1e-5f);
    }
    __syncthreads();
    // normalize -> rowBuf (r1, swizzled as [16 b][96 chunks], chunk = bl*96 + (kidx^(bl&7)))
    #pragma unroll
    for (int mi = 0; mi < 3; ++mi) {
        #pragma unroll
        for (int r = 0; r < 4; ++r) {
            int rho = mi * 16 + q * 4 + r;
            float mean = mvS[rho * 2], rstd = mvS[rho * 2 + 1];
            int bl = rho / 3, sl = rho - bl * 3;
            #pragma unroll
            for (int ni = 0; ni < 4; ++ni) {
                int col = wv * 64 + ni * 16 + l15;
                float x = (acc[mi][ni][r] - mean) * rstd * gnv[ni] + gbv[ni];
                int k = sl * 256 + col;
                int kidx = k >> 3, wn = k & 7;
                r1[(bl * 96 + (kidx ^ (bl & 7))) * 8 + wn] = f2bf(x);
            }
        }
    }
    __syncthreads();
    // gating MFMA: h1[16 b][64] = attended_flat(16x768) @ g1w.T ; wave wv owns cols wv*16..+15
    fx4 ag = zero;
    for (int kt = 0; kt < 24; ++kt) {
        int bl = l15;
        int kidx = kt * 4 + q;
        bf16x8 afr = *(const bf16x8*)(r1 + (bl * 96 + (kidx ^ (bl & 7))) * 8);
        int n = wv * 16 + l15;
        bf16x8 bfr2 = *(const bf16x8*)(g1w + (size_t)n * 768 + kt * 32 + q * 8);
        ag = MFMA_BF16(afr, bfr2, ag);
    }
    #pragma unroll
    for (int r = 0; r < 4; ++r) {
        int bl = q * 4 + r, n = wv * 16 + l15;
        float x = ag[r] + g1b[n];
        h1S[bl * 64 + n] = 0.5f * x * (1.f + erff(x * 0.70710678118f));
    }
    __syncthreads();
    if (t < 48) {  // logits: t = bl*3 + s
        int bl = t / 3, s = t - bl * 3;
        float a = g2b[s];
        #pragma unroll
        for (int k = 0; k < 64; ++k) a += h1S[bl * 64 + k] * g2w[s * 64 + k];
        lgS[t] = a;
    }
    __syncthreads();
    if (t < 48) {
        int bl = t / 3, s = t - bl * 3;
        float l0 = lgS[bl * 3], l1 = lgS[bl * 3 + 1], l2 = lgS[bl * 3 + 2];
        float m = fmaxf(l0, fmaxf(l1, l2));
        float e0 = __expf(l0 - m), e1 = __expf(l1 - m), e2 = __expf(l2 - m);
        float inv = 1.f / (e0 + e1 + e2);
        float gsel = ((s == 0) ? e0 : (s == 1) ? e1 : e2) * inv;
        gateS[t] = gsel;
        outG[(size_t)(b0 + bl) * 3 + s] = gsel;
    }
    __syncthreads();
    // fused = sum_s gate[s] * attended[s]
    #pragma unroll
    for (int it = 0; it < 2; ++it) {
        int idx = t + it * 256;
        int b = idx >> 5, c = idx & 31;
        float g0 = gateS[b * 3], g1 = gateS[b * 3 + 1], g2 = gateS[b * 3 + 2];
        float o[8];
        #pragma unroll
        for (int e = 0; e < 8; ++e) o[e] = 0.f;
        #pragma unroll
        for (int s = 0; s < 3; ++s) {
            float gw = (s == 0) ? g0 : (s == 1) ? g1 : g2;
            int kidx = s * 32 + c;
            uint4 raw = *(const uint4*)(r1 + (b * 96 + (kidx ^ (b & 7))) * 8);
            unsigned uu[4] = {raw.x, raw.y, raw.z, raw.w};
            #pragma unroll
            for (int pr = 0; pr < 4; ++pr) {
                union { unsigned u; float f; } lo, hi;
                lo.u = uu[pr] << 16; hi.u = uu[pr] & 0xffff0000u;
                o[2 * pr]     += gw * lo.f;
                o[2 * pr + 1] += gw * hi.f;
            }
        }
        float* op = outF + (size_t)(b0 + b) * 256 + c * 8;
        float4 v0; v0.x = o[0]; v0.y = o[1]; v0.z = o[2]; v0.w = o[3];
        float4 v1; v1.x = o[4]; v1.y = o[5]; v1.z = o[6]; v1.w = o[7];
        *(float4*)op = v0;
        *(float4*)(op + 4) = v1;
    }
}

extern "C" void kernel_launch(void* const* d_in, const int* in_sizes, int n_in,
                              void* d_out, int out_size, void* d_ws, size_t ws_size,
                              hipStream_t stream) {
    (void)in_sizes; (void)n_in; (void)out_size; (void)ws_size;
    const float* fv   = (const float*)d_in[0];
    const float* fs   = (const float*)d_in[1];
    const float* fc   = (const float*)d_in[2];
    const float* Wv   = (const float*)d_in[3];
    const float* bv   = (const float*)d_in[4];
    const float* gv   = (const float*)d_in[5];
    const float* bev  = (const float*)d_in[6];
    const float* Ws   = (const float*)d_in[7];
    const float* bs   = (const float*)d_in[8];
    const float* gs   = (const float*)d_in[9];
    const float* bes  = (const float*)d_in[10];
    const float* Wc   = (const float*)d_in[11];
    const float* bc   = (const float*)d_in[12];
    const float* gc_  = (const float*)d_in[13];
    const float* bec  = (const float*)d_in[14];
    const float* in_w = (const float*)d_in[15];
    const float* in_b = (const float*)d_in[16];
    const float* out_w= (const float*)d_in[17];
    const float* out_b= (const float*)d_in[18];
    const float* gn   = (const float*)d_in[19];
    const float* gb   = (const float*)d_in[20];
    const float* g1w  = (const float*)d_in[21];
    const float* g1b  = (const float*)d_in[22];
    const float* g2w  = (const float*)d_in[23];
    const float* g2b  = (const float*)d_in[24];

    u16* w0    = (u16*)d_ws;
    u16* wWv   = w0;               // 524288
    u16* wWs   = w0 + 524288;      // 262144
    u16* wWc   = w0 + 786432;      // 131072
    u16* wIn   = w0 + 917504;      // 196608
    u16* wOut  = w0 + 1114112;     // 65536
    u16* wG1   = w0 + 1179648;     // 49152
    u16* stack = w0 + 1228800;     // 49152*256
    u16* qkv   = w0 + 13811712;    // 49152*768
    u16* ctx   = w0 + 51560448;    // 49152*256  (total 64143360 u16 = ~128.3 MB)
    float* outF = (float*)d_out;
    float* outG = outF + (size_t)16384 * 256;

    cvt_w<<<4800, 256, 0, stream>>>(Wv, Ws, Wc, in_w, out_w, g1w, w0);
    gemm_ln<<<768, 256, 0, stream>>>(fv, fs, fc, wWv, wWs, wWc,
                                     bv, gv, bev, bs, gs, bes, bc, gc_, bec, stack);
    gemm_qkv<<<dim3(6, 384), 256, 0, stream>>>(stack, wIn, in_b, qkv);
    attn_k<<<2048, 256, 0, stream>>>(qkv, ctx);
    outproj_k<<<1024, 256, 0, stream>>>(ctx, wOut, out_b, stack, gn, gb,
                                        wG1, g1b, g2w, g2b, outF, outG);
}

// Round 5
// 463.820 us; speedup vs baseline: 1.1947x; 1.1947x over previous
//
#include <hip/hip_runtime.h>
#include <math.h>

// GatedCrossAttentionFusion on MI355X (gfx950), bf16 MFMA pipeline.
// B=16384, VD=2048, SD=1024, CD=512, H=256, HEADS=4, DH=64.
//
// Pipeline (all bf16 intermediates in ws):
//  K0 cvt_w     : fp32->bf16 weight conversion (Wv,Ws,Wc,in_w,out_w,g1w)
//  K1 gemm_ln   : {fv,fs,fc} @ W.T + bias -> LayerNorm -> stack (B*3,256) bf16
//  K2 gemm_qkv  : stack @ in_w.T + in_b -> qkv (B*3,768) bf16
//  K3 attn_k    : per-b 4-head 3x3 attention -> ctx (B*3,256) bf16
//  K4 outproj_k : ctx @ out_w.T + out_b + stack -> LN -> gating MLP -> fused+gates
//
// R0-R4 lesson: gemm_ln time tracks TOTAL STAGED BYTES through the VMEM path
// (R0/R2/R3: three schedules, same 130us; R1 steps x2 same bytes +16%; R4
// reg-direct +62%). B-panel re-staging (1/BM scaling) was 2/3 of staged bytes.
// R5: bigger tiles (K1: BM=128, K2: 128x256) cut staged bytes 34-50%; keep the
// simple 2-barrier single-buffer schedule (proven schedule-insensitive).

typedef unsigned short u16;
typedef __bf16 bf16x8 __attribute__((ext_vector_type(8)));
typedef float fx4 __attribute__((ext_vector_type(4)));

#define MFMA_BF16(A_, B_, C_) __builtin_amdgcn_mfma_f32_16x16x32_bf16((A_), (B_), (C_), 0, 0, 0)

__device__ __forceinline__ float bf2f(u16 s) {
    union { float f; unsigned u; } c; c.u = ((unsigned)s) << 16; return c.f;
}
__device__ __forceinline__ u16 f2bf(float f) {
    union { float f; unsigned u; } c; c.f = f;
    return (u16)((c.u + 0x7fffu + ((c.u >> 16) & 1u)) >> 16);
}
// a,b are packed bf16 pairs (little-endian: low u16 = even element)
__device__ __forceinline__ float bfpair_dot(unsigned a, unsigned b) {
    union { unsigned u; float f; } al, ah, bl, bh;
    al.u = a << 16; ah.u = a & 0xffff0000u;
    bl.u = b << 16; bh.u = b & 0xffff0000u;
    return al.f * bl.f + ah.f * bh.f;
}
__device__ __forceinline__ void gld16(void* l, const void* g) {
    __builtin_amdgcn_global_load_lds((const __attribute__((address_space(1))) void*)g,
                                     (__attribute__((address_space(3))) void*)l, 16, 0, 0);
}

// ---------------------------------------------------------------- K0: weights
__global__ __launch_bounds__(256) void cvt_w(const float* Wv, const float* Ws, const float* Wc,
                                             const float* inw, const float* outw, const float* g1w,
                                             u16* dst) {
    int idx = blockIdx.x * 256 + threadIdx.x;  // grid covers exactly 1228800
    const float* src; int rel;
    if      (idx <  524288) { src = Wv;   rel = idx; }
    else if (idx <  786432) { src = Ws;   rel = idx -  524288; }
    else if (idx <  917504) { src = Wc;   rel = idx -  786432; }
    else if (idx < 1114112) { src = inw;  rel = idx -  917504; }
    else if (idx < 1179648) { src = outw; rel = idx - 1114112; }
    else                    { src = g1w;  rel = idx - 1179648; }
    dst[idx] = f2bf(src[rel]);
}

// ------------------------------------------------- K1: input GEMM + LayerNorm
// BM=128, BN=256(=H), BK=32, 4 waves (wave w owns cols w*64..w*64+63; each wave
// computes all 128 rows -> acc[8][4]). 1D grid of 384 blocks, longest-job-first:
// bid<128 slot0 (K=2048), <256 slot1 (K=1024), else slot2 (K=512).
// BM=128 halves the B-panel re-staging bytes vs BM=64 (the dominant staged
// traffic) and halves block-step count.
__global__ __launch_bounds__(256, 2) void gemm_ln(
    const float* fv, const float* fs, const float* fc,
    const u16* wWv, const u16* wWs, const u16* wWc,
    const float* bv, const float* gv, const float* bev,
    const float* bs, const float* gs, const float* bes,
    const float* bc, const float* gc_, const float* bec,
    u16* stack) {
    // loop: sA bf16 [128][40] @0 (10240B), sB @10240 (16KB, swizzled chunks)
    // epilogue: sC [128][256] bf16 @0 (64KB overlay), red arrays @65536.
    __shared__ alignas(16) char smem[70656];
    u16* sA = (u16*)smem;
    u16* sB = (u16*)(smem + 10240);
    u16* sC = (u16*)smem;
    float* redS = (float*)(smem + 65536);   // [128][4]
    float* redQ = (float*)(smem + 67584);   // [128][4]
    float* mvS  = (float*)(smem + 69632);   // [128][2] mean,rstd

    int bid = blockIdx.x;
    int slot, mblk;
    if (bid < 128)      { slot = 0; mblk = bid; }
    else if (bid < 256) { slot = 1; mblk = bid - 128; }
    else                { slot = 2; mblk = bid - 256; }

    const float* A; const u16* W; const float* bias; const float* gg; const float* be; int K;
    if (slot == 0)      { A = fv; W = wWv; bias = bv; gg = gv;  be = bev; K = 2048; }
    else if (slot == 1) { A = fs; W = wWs; bias = bs; gg = gs;  be = bes; K = 1024; }
    else                { A = fc; W = wWc; bias = bc; gg = gc_; be = bec; K = 512;  }

    int t = threadIdx.x, wv = t >> 6, ln = t & 63, q = ln >> 4, l15 = ln & 15;
    int m0 = mblk * 128;

    fx4 zero = {0.f, 0.f, 0.f, 0.f};
    fx4 acc[8][4];
    #pragma unroll
    for (int mi = 0; mi < 8; ++mi)
        #pragma unroll
        for (int ni = 0; ni < 4; ++ni) acc[mi][ni] = zero;

    // A staging: 128 rows x 32 fp32; thread t handles row t>>1, half (t&1)*16
    int rowA = t >> 1, ca = t & 1;
    const float* aBase = A + (size_t)(m0 + rowA) * K + ca * 16;
    u16* sAw = sA + rowA * 40 + ca * 16;

    // B staging: 1024 x16B chunks, pos p of row n holds k-chunk p^((n>>1)&3)
    int bN[4], bKc[4];
    #pragma unroll
    for (int i = 0; i < 4; ++i) {
        int d = wv * 256 + i * 64 + ln;
        bN[i] = d >> 2;
        bKc[i] = (d & 3) ^ ((bN[i] >> 1) & 3);
    }

    int niter = K >> 5;
    for (int kt = 0; kt < niter; ++kt) {
        // B DMA first (stays in flight while A converts)
        #pragma unroll
        for (int i = 0; i < 4; ++i)
            gld16((char*)sB + (wv * 256 + i * 64) * 16, W + (size_t)bN[i] * K + kt * 32 + bKc[i] * 8);
        // A: global->reg->cvt->LDS (16 fp32 per thread)
        float4 f0 = *(const float4*)(aBase + kt * 32);
        float4 f1 = *(const float4*)(aBase + kt * 32 + 4);
        float4 f2 = *(const float4*)(aBase + kt * 32 + 8);
        float4 f3 = *(const float4*)(aBase + kt * 32 + 12);
        union { u16 us[8]; uint4 v; } p0, p1;
        p0.us[0] = f2bf(f0.x); p0.us[1] = f2bf(f0.y); p0.us[2] = f2bf(f0.z); p0.us[3] = f2bf(f0.w);
        p0.us[4] = f2bf(f1.x); p0.us[5] = f2bf(f1.y); p0.us[6] = f2bf(f1.z); p0.us[7] = f2bf(f1.w);
        p1.us[0] = f2bf(f2.x); p1.us[1] = f2bf(f2.y); p1.us[2] = f2bf(f2.z); p1.us[3] = f2bf(f2.w);
        p1.us[4] = f2bf(f3.x); p1.us[5] = f2bf(f3.y); p1.us[6] = f2bf(f3.z); p1.us[7] = f2bf(f3.w);
        *(uint4*)sAw = p0.v;
        *(uint4*)(sAw + 8) = p1.v;
        __syncthreads();
        bf16x8 af[8], bfr[4];
        #pragma unroll
        for (int mi = 0; mi < 8; ++mi)
            af[mi] = *(const bf16x8*)(sA + (mi * 16 + l15) * 40 + q * 8);
        #pragma unroll
        for (int ni = 0; ni < 4; ++ni) {
            int n = wv * 64 + ni * 16 + l15;
            int ch = n * 4 + (q ^ ((n >> 1) & 3));
            bfr[ni] = *(const bf16x8*)(sB + ch * 8);
        }
        #pragma unroll
        for (int mi = 0; mi < 8; ++mi)
            #pragma unroll
            for (int ni = 0; ni < 4; ++ni)
                acc[mi][ni] = MFMA_BF16(af[mi], bfr[ni], acc[mi][ni]);
        __syncthreads();
    }

    // epilogue: bias, LN stats from registers, normalize, write bf16
    float biasv[4], gvv[4], bevv[4];
    #pragma unroll
    for (int ni = 0; ni < 4; ++ni) {
        int col = wv * 64 + ni * 16 + l15;
        biasv[ni] = bias[col]; gvv[ni] = gg[col]; bevv[ni] = be[col];
    }
    #pragma unroll
    for (int mi = 0; mi < 8; ++mi)
        #pragma unroll
        for (int ni = 0; ni < 4; ++ni)
            #pragma unroll
            for (int r = 0; r < 4; ++r) acc[mi][ni][r] += biasv[ni];
    #pragma unroll
    for (int mi = 0; mi < 8; ++mi) {
        #pragma unroll
        for (int r = 0; r < 4; ++r) {
            float s = 0.f, qq = 0.f;
            #pragma unroll
            for (int ni = 0; ni < 4; ++ni) { float x = acc[mi][ni][r]; s += x; qq += x * x; }
            #pragma unroll
            for (int m = 1; m < 16; m <<= 1) { s += __shfl_xor(s, m, 64); qq += __shfl_xor(qq, m, 64); }
            if (l15 == 0) { int rho = mi * 16 + q * 4 + r; redS[rho * 4 + wv] = s; redQ[rho * 4 + wv] = qq; }
        }
    }
    __syncthreads();
    if (t < 128) {
        float s = redS[t * 4] + redS[t * 4 + 1] + redS[t * 4 + 2] + redS[t * 4 + 3];
        float qq = redQ[t * 4] + redQ[t * 4 + 1] + redQ[t * 4 + 2] + redQ[t * 4 + 3];
        float mean = s * (1.f / 256.f);
        float var = qq * (1.f / 256.f) - mean * mean;
        mvS[t * 2] = mean; mvS[t * 2 + 1] = rsqrtf(var + 1e-5f);
    }
    __syncthreads();
    #pragma unroll
    for (int mi = 0; mi < 8; ++mi) {
        #pragma unroll
        for (int r = 0; r < 4; ++r) {
            int rho = mi * 16 + q * 4 + r;
            float mean = mvS[rho * 2], rstd = mvS[rho * 2 + 1];
            #pragma unroll
            for (int ni = 0; ni < 4; ++ni) {
                int col = wv * 64 + ni * 16 + l15;
                float x = (acc[mi][ni][r] - mean) * rstd * gvv[ni] + bevv[ni];
                sC[rho * 256 + col] = f2bf(x);
            }
        }
    }
    __syncthreads();
    u16* outp = stack + (size_t)m0 * 768 + slot * 256;
    #pragma unroll
    for (int it = 0; it < 16; ++it) {
        int idx = t + it * 256;
        int row = idx >> 5, c = idx & 31;
        uint4 v = *(const uint4*)(sC + row * 256 + c * 8);
        *(uint4*)(outp + (size_t)row * 768 + c * 8) = v;
    }
}

// ------------------------------------------------------ K2: qkv = stack@in_w.T
// M=49152, K=256, N=768. BM=128, BN=256, 4 waves in 2x2 (wave = 64 rows x 128
// cols, acc[4][8]). Halves staged bytes vs 128x128 (fewer panel re-reads).
__global__ __launch_bounds__(256, 2) void gemm_qkv(const u16* stack, const u16* W, const float* in_b,
                                                   u16* qkv) {
    // loop: sA @0 (8KB, 512 chunks), sB @8192 (16KB, 1024 chunks)
    // epilogue: sC [128][256] bf16 @0 (64KB overlay)
    __shared__ alignas(16) char smem[65536];
    u16* sA = (u16*)smem;
    u16* sB = (u16*)(smem + 8192);
    u16* sC = (u16*)smem;

    int t = threadIdx.x, wv = t >> 6, ln = t & 63, q = ln >> 4, l15 = ln & 15;
    int n0 = blockIdx.x * 256, m0 = blockIdx.y * 128;
    int wr = wv >> 1, wc = wv & 1;

    fx4 zero = {0.f, 0.f, 0.f, 0.f};
    fx4 acc[4][8];
    #pragma unroll
    for (int mi = 0; mi < 4; ++mi)
        #pragma unroll
        for (int ni = 0; ni < 8; ++ni) acc[mi][ni] = zero;

    // A staging map: 512 chunks (128 rows x 4 chunks-of-8)
    int aR[2], aKc[2];
    #pragma unroll
    for (int i = 0; i < 2; ++i) {
        int d = wv * 128 + i * 64 + ln;
        aR[i] = d >> 2;
        aKc[i] = (d & 3) ^ ((aR[i] >> 1) & 3);
    }
    // B staging map: 1024 chunks (256 rows x 4 chunks-of-8)
    int bN[4], bKc[4];
    #pragma unroll
    for (int i = 0; i < 4; ++i) {
        int d = wv * 256 + i * 64 + ln;
        bN[i] = d >> 2;
        bKc[i] = (d & 3) ^ ((bN[i] >> 1) & 3);
    }

    for (int kt = 0; kt < 8; ++kt) {
        #pragma unroll
        for (int i = 0; i < 2; ++i)
            gld16((char*)sA + (wv * 128 + i * 64) * 16,
                  stack + (size_t)(m0 + aR[i]) * 256 + kt * 32 + aKc[i] * 8);
        #pragma unroll
        for (int i = 0; i < 4; ++i)
            gld16((char*)sB + (wv * 256 + i * 64) * 16,
                  W + (size_t)(n0 + bN[i]) * 256 + kt * 32 + bKc[i] * 8);
        __syncthreads();
        bf16x8 af[4], bfr[8];
        #pragma unroll
        for (int mi = 0; mi < 4; ++mi) {
            int r = wr * 64 + mi * 16 + l15;
            int ch = r * 4 + (q ^ ((r >> 1) & 3));
            af[mi] = *(const bf16x8*)(sA + ch * 8);
        }
        #pragma unroll
        for (int ni = 0; ni < 8; ++ni) {
            int n = wc * 128 + ni * 16 + l15;
            int ch = n * 4 + (q ^ ((n >> 1) & 3));
            bfr[ni] = *(const bf16x8*)(sB + ch * 8);
        }
        #pragma unroll
        for (int mi = 0; mi < 4; ++mi)
            #pragma unroll
            for (int ni = 0; ni < 8; ++ni)
                acc[mi][ni] = MFMA_BF16(af[mi], bfr[ni], acc[mi][ni]);
        __syncthreads();
    }

    float biasv[8];
    #pragma unroll
    for (int ni = 0; ni < 8; ++ni) biasv[ni] = in_b[n0 + wc * 128 + ni * 16 + l15];
    #pragma unroll
    for (int mi = 0; mi < 4; ++mi)
        #pragma unroll
        for (int ni = 0; ni < 8; ++ni)
            #pragma unroll
            for (int r = 0; r < 4; ++r) {
                int rl = wr * 64 + mi * 16 + q * 4 + r;
                int cl = wc * 128 + ni * 16 + l15;
                sC[rl * 256 + cl] = f2bf(acc[mi][ni][r] + biasv[ni]);
            }
    __syncthreads();
    #pragma unroll
    for (int it = 0; it < 16; ++it) {
        int idx = t + it * 256;
        int row = idx >> 5, c = idx & 31;
        uint4 v = *(const uint4*)(sC + row * 256 + c * 8);
        *(uint4*)(qkv + (size_t)(m0 + row) * 768 + n0 + c * 8) = v;
    }
}

// ------------------------------------------------------------- K3: attention
// 8 b's per block. qkv row per (b,i): [q(256)|k(256)|v(256)].
__global__ __launch_bounds__(256) void attn_k(const u16* qkv, u16* ctx) {
    __shared__ alignas(16) char smem[38016];
    u16* qs = (u16*)smem;                 // 8*2304 bf16
    float* sS = (float*)(smem + 36864);   // 288 scores/probs: [b][h][i][j]

    int t = threadIdx.x, wv = t >> 6, ln = t & 63;
    size_t base = (size_t)blockIdx.x * 8 * 2304;
    #pragma unroll
    for (int i = 0; i < 9; ++i) {
        int d = wv * 576 + i * 64;
        gld16((char*)smem + (size_t)d * 16, qkv + base + (size_t)(d + ln) * 8);
    }
    __syncthreads();
    // scores: 288 items = 8b*4h*9(i,j)
    #pragma unroll
    for (int it = 0; it < 2; ++it) {
        int idx = t + it * 256;
        if (idx < 288) {
            int b = idx / 36, rem = idx % 36, h = rem / 9, pp = rem % 9, i = pp / 3, j = pp % 3;
            const u16* qp = qs + b * 2304 + i * 768 + h * 64;
            const u16* kp = qs + b * 2304 + j * 768 + 256 + h * 64;
            float acc = 0.f;
            #pragma unroll
            for (int c = 0; c < 8; ++c) {
                uint4 qa = *(const uint4*)(qp + c * 8);
                uint4 ka = *(const uint4*)(kp + c * 8);
                acc += bfpair_dot(qa.x, ka.x) + bfpair_dot(qa.y, ka.y) +
                       bfpair_dot(qa.z, ka.z) + bfpair_dot(qa.w, ka.w);
            }
            sS[idx] = acc * 0.125f;  // /sqrt(64)
        }
    }
    __syncthreads();
    if (t < 96) {  // softmax over j, t = b*12 + h*3 + i
        int b3 = t * 3;
        float s0 = sS[b3], s1 = sS[b3 + 1], s2 = sS[b3 + 2];
        float m = fmaxf(s0, fmaxf(s1, s2));
        float e0 = __expf(s0 - m), e1 = __expf(s1 - m), e2 = __expf(s2 - m);
        float inv = 1.f / (e0 + e1 + e2);
        sS[b3] = e0 * inv; sS[b3 + 1] = e1 * inv; sS[b3 + 2] = e2 * inv;
    }
    __syncthreads();
    // ctx: 768 items = 8b * 3i * 32 chunks-of-8
    #pragma unroll
    for (int it = 0; it < 3; ++it) {
        int idx = t + it * 256;
        int b = idx / 96, rem = idx % 96, i = rem / 32, c = rem & 31, h = c >> 3;
        int pbase = b * 36 + h * 9 + i * 3;
        float o[8];
        #pragma unroll
        for (int e = 0; e < 8; ++e) o[e] = 0.f;
        #pragma unroll
        for (int j = 0; j < 3; ++j) {
            float p = sS[pbase + j];
            uint4 va = *(const uint4*)(qs + b * 2304 + j * 768 + 512 + c * 8);
            unsigned uu[4] = {va.x, va.y, va.z, va.w};
            #pragma unroll
            for (int pr = 0; pr < 4; ++pr) {
                union { unsigned u; float f; } lo, hi;
                lo.u = uu[pr] << 16; hi.u = uu[pr] & 0xffff0000u;
                o[2 * pr]     += p * lo.f;
                o[2 * pr + 1] += p * hi.f;
            }
        }
        union { u16 us[8]; uint4 v; } pk;
        #pragma unroll
        for (int e = 0; e < 8; ++e) pk.us[e] = f2bf(o[e]);
        *(uint4*)(ctx + (size_t)(blockIdx.x * 8 + b) * 768 + i * 256 + c * 8) = pk.v;
    }
}

// -------------------- K4: out-proj + residual + LN + gating MLP + fused output
// BM=48 (16 b's), BN=256, K=256. region1: ctxA -> stackS -> rowBuf(attended,swizzled)
__global__ __launch_bounds__(256) void outproj_k(
    const u16* ctx, const u16* W, const float* out_b, const u16* stack,
    const float* gn, const float* gb, const u16* g1w, const float* g1b,
    const float* g2w, const float* g2b, float* outF, float* outG) {
    __shared__ alignas(16) char smem[40960];
    u16* r1 = (u16*)smem;                         // 24576B
    u16* sB = (u16*)(smem + 24576);               // 16384B (k-loop)
    float* redS = (float*)(smem + 24576);         // 48*4
    float* redQ = redS + 192;
    float* mvS = redQ + 192;                      // 48*2
    float* h1S = (float*)(smem + 26624);          // [16][64]
    float* lgS = (float*)(smem + 30720);          // 48 logits
    float* gateS = lgS + 48;                      // 48 gates

    int t = threadIdx.x, wv = t >> 6, ln = t & 63, q = ln >> 4, l15 = ln & 15;
    int gr0 = blockIdx.x * 48, b0 = blockIdx.x * 16;

    // stage full ctx tile [48][256] once, chunk pos p holds k-chunk p^(row&7)
    #pragma unroll
    for (int i = 0; i < 6; ++i) {
        int d = wv * 384 + i * 64 + ln;
        int row = d >> 5, p = d & 31;
        int kc = p ^ (row & 7);
        gld16((char*)r1 + (wv * 384 + i * 64) * 16, ctx + (size_t)(gr0 + row) * 256 + kc * 8);
    }
    __syncthreads();

    fx4 zero = {0.f, 0.f, 0.f, 0.f};
    fx4 acc[3][4];
    #pragma unroll
    for (int mi = 0; mi < 3; ++mi)
        #pragma unroll
        for (int ni = 0; ni < 4; ++ni) acc[mi][ni] = zero;

    for (int kt = 0; kt < 8; ++kt) {
        #pragma unroll
        for (int i = 0; i < 4; ++i) {
            int d = wv * 256 + i * 64 + ln;
            int n = d >> 2, p = d & 3;
            int kc = p ^ ((n >> 1) & 3);
            gld16((char*)sB + (wv * 256 + i * 64) * 16, W + (size_t)n * 256 + kt * 32 + kc * 8);
        }
        __syncthreads();
        bf16x8 af[3], bfr[4];
        #pragma unroll
        for (int mi = 0; mi < 3; ++mi) {
            int row = mi * 16 + l15;
            int ch = row * 32 + ((kt * 4 + q) ^ (row & 7));
            af[mi] = *(const bf16x8*)(r1 + ch * 8);
        }
        #pragma unroll
        for (int ni = 0; ni < 4; ++ni) {
            int n = wv * 64 + ni * 16 + l15;
            int ch = n * 4 + (q ^ ((n >> 1) & 3));
            bfr[ni] = *(const bf16x8*)(sB + ch * 8);
        }
        #pragma unroll
        for (int mi = 0; mi < 3; ++mi)
            #pragma unroll
            for (int ni = 0; ni < 4; ++ni)
                acc[mi][ni] = MFMA_BF16(af[mi], bfr[ni], acc[mi][ni]);
        __syncthreads();
    }

    // stage stack tile [48][256] (contiguous in global) into r1
    #pragma unroll
    for (int i = 0; i < 6; ++i) {
        int d = wv * 384 + i * 64 + ln;
        gld16((char*)r1 + (wv * 384 + i * 64) * 16, stack + (size_t)gr0 * 256 + (size_t)d * 8);
    }
    __syncthreads();

    float obv[4], gnv[4], gbv[4];
    #pragma unroll
    for (int ni = 0; ni < 4; ++ni) {
        int col = wv * 64 + ni * 16 + l15;
        obv[ni] = out_b[col]; gnv[ni] = gn[col]; gbv[ni] = gb[col];
    }
    #pragma unroll
    for (int mi = 0; mi < 3; ++mi)
        #pragma unroll
        for (int ni = 0; ni < 4; ++ni)
            #pragma unroll
            for (int r = 0; r < 4; ++r) {
                int rho = mi * 16 + q * 4 + r;
                int col = wv * 64 + ni * 16 + l15;
                acc[mi][ni][r] += obv[ni] + bf2f(r1[rho * 256 + col]);
            }
    // LN stats
    #pragma unroll
    for (int mi = 0; mi < 3; ++mi) {
        #pragma unroll
        for (int r = 0; r < 4; ++r) {
            float s = 0.f, qq = 0.f;
            #pragma unroll
            for (int ni = 0; ni < 4; ++ni) { float x = acc[mi][ni][r]; s += x; qq += x * x; }
            #pragma unroll
            for (int m = 1; m < 16; m <<= 1) { s += __shfl_xor(s, m, 64); qq += __shfl_xor(qq, m, 64); }
            if (l15 == 0) { int rho = mi * 16 + q * 4 + r; redS[rho * 4 + wv] = s; redQ[rho * 4 + wv] = qq; }
        }
    }
    __syncthreads();
    if (t < 48) {
        float s = redS[t * 4] + redS[t * 4 + 1] + redS[t * 4 + 2] + redS[t * 4 + 3];
        float qq = redQ[t * 4] + redQ[t * 4 + 1] + redQ[t * 4 + 2] + redQ[t * 4 + 3];
        float mean = s * (1.f / 256.f);
        float var = qq * (1.f / 256.f) - mean * mean;
        mvS[t * 2] = mean; mvS[t * 2 + 1] = rsqrtf(var + 1e-5f);
    }
    __syncthreads();
    // normalize -> rowBuf (r1, swizzled as [16 b][96 chunks], chunk = bl*96 + (kidx^(bl&7)))
    #pragma unroll
    for (int mi = 0; mi < 3; ++mi) {
        #pragma unroll
        for (int r = 0; r < 4; ++r) {
            int rho = mi * 16 + q * 4 + r;
            float mean = mvS[rho * 2], rstd = mvS[rho * 2 + 1];
            int bl = rho / 3, sl = rho - bl * 3;
            #pragma unroll
            for (int ni = 0; ni < 4; ++ni) {
                int col = wv * 64 + ni * 16 + l15;
                float x = (acc[mi][ni][r] - mean) * rstd * gnv[ni] + gbv[ni];
                int k = sl * 256 + col;
                int kidx = k >> 3, wn = k & 7;
                r1[(bl * 96 + (kidx ^ (bl & 7))) * 8 + wn] = f2bf(x);
            }
        }
    }
    __syncthreads();
    // gating MFMA: h1[16 b][64] = attended_flat(16x768) @ g1w.T ; wave wv owns cols wv*16..+15
    fx4 ag = zero;
    for (int kt = 0; kt < 24; ++kt) {
        int bl = l15;
        int kidx = kt * 4 + q;
        bf16x8 afr = *(const bf16x8*)(r1 + (bl * 96 + (kidx ^ (bl & 7))) * 8);
        int n = wv * 16 + l15;
        bf16x8 bfr2 = *(const bf16x8*)(g1w + (size_t)n * 768 + kt * 32 + q * 8);
        ag = MFMA_BF16(afr, bfr2, ag);
    }
    #pragma unroll
    for (int r = 0; r < 4; ++r) {
        int bl = q * 4 + r, n = wv * 16 + l15;
        float x = ag[r] + g1b[n];
        h1S[bl * 64 + n] = 0.5f * x * (1.f + erff(x * 0.70710678118f));
    }
    __syncthreads();
    if (t < 48) {  // logits: t = bl*3 + s
        int bl = t / 3, s = t - bl * 3;
        float a = g2b[s];
        #pragma unroll
        for (int k = 0; k < 64; ++k) a += h1S[bl * 64 + k] * g2w[s * 64 + k];
        lgS[t] = a;
    }
    __syncthreads();
    if (t < 48) {
        int bl = t / 3, s = t - bl * 3;
        float l0 = lgS[bl * 3], l1 = lgS[bl * 3 + 1], l2 = lgS[bl * 3 + 2];
        float m = fmaxf(l0, fmaxf(l1, l2));
        float e0 = __expf(l0 - m), e1 = __expf(l1 - m), e2 = __expf(l2 - m);
        float inv = 1.f / (e0 + e1 + e2);
        float gsel = ((s == 0) ? e0 : (s == 1) ? e1 : e2) * inv;
        gateS[t] = gsel;
        outG[(size_t)(b0 + bl) * 3 + s] = gsel;
    }
    __syncthreads();
    // fused = sum_s gate[s] * attended[s]
    #pragma unroll
    for (int it = 0; it < 2; ++it) {
        int idx = t + it * 256;
        int b = idx >> 5, c = idx & 31;
        float g0 = gateS[b * 3], g1 = gateS[b * 3 + 1], g2 = gateS[b * 3 + 2];
        float o[8];
        #pragma unroll
        for (int e = 0; e < 8; ++e) o[e] = 0.f;
        #pragma unroll
        for (int s = 0; s < 3; ++s) {
            float gw = (s == 0) ? g0 : (s == 1) ? g1 : g2;
            int kidx = s * 32 + c;
            uint4 raw = *(const uint4*)(r1 + (b * 96 + (kidx ^ (b & 7))) * 8);
            unsigned uu[4] = {raw.x, raw.y, raw.z, raw.w};
            #pragma unroll
            for (int pr = 0; pr < 4; ++pr) {
                union { unsigned u; float f; } lo, hi;
                lo.u = uu[pr] << 16; hi.u = uu[pr] & 0xffff0000u;
                o[2 * pr]     += gw * lo.f;
                o[2 * pr + 1] += gw * hi.f;
            }
        }
        float* op = outF + (size_t)(b0 + b) * 256 + c * 8;
        float4 v0; v0.x = o[0]; v0.y = o[1]; v0.z = o[2]; v0.w = o[3];
        float4 v1; v1.x = o[4]; v1.y = o[5]; v1.z = o[6]; v1.w = o[7];
        *(float4*)op = v0;
        *(float4*)(op + 4) = v1;
    }
}

extern "C" void kernel_launch(void* const* d_in, const int* in_sizes, int n_in,
                              void* d_out, int out_size, void* d_ws, size_t ws_size,
                              hipStream_t stream) {
    (void)in_sizes; (void)n_in; (void)out_size; (void)ws_size;
    const float* fv   = (const float*)d_in[0];
    const float* fs   = (const float*)d_in[1];
    const float* fc   = (const float*)d_in[2];
    const float* Wv   = (const float*)d_in[3];
    const float* bv   = (const float*)d_in[4];
    const float* gv   = (const float*)d_in[5];
    const float* bev  = (const float*)d_in[6];
    const float* Ws   = (const float*)d_in[7];
    const float* bs   = (const float*)d_in[8];
    const float* gs   = (const float*)d_in[9];
    const float* bes  = (const float*)d_in[10];
    const float* Wc   = (const float*)d_in[11];
    const float* bc   = (const float*)d_in[12];
    const float* gc_  = (const float*)d_in[13];
    const float* bec  = (const float*)d_in[14];
    const float* in_w = (const float*)d_in[15];
    const float* in_b = (const float*)d_in[16];
    const float* out_w= (const float*)d_in[17];
    const float* out_b= (const float*)d_in[18];
    const float* gn   = (const float*)d_in[19];
    const float* gb   = (const float*)d_in[20];
    const float* g1w  = (const float*)d_in[21];
    const float* g1b  = (const float*)d_in[22];
    const float* g2w  = (const float*)d_in[23];
    const float* g2b  = (const float*)d_in[24];

    u16* w0    = (u16*)d_ws;
    u16* wWv   = w0;               // 524288
    u16* wWs   = w0 + 524288;      // 262144
    u16* wWc   = w0 + 786432;      // 131072
    u16* wIn   = w0 + 917504;      // 196608
    u16* wOut  = w0 + 1114112;     // 65536
    u16* wG1   = w0 + 1179648;     // 49152
    u16* stack = w0 + 1228800;     // 49152*256
    u16* qkv   = w0 + 13811712;    // 49152*768
    u16* ctx   = w0 + 51560448;    // 49152*256  (total 64143360 u16 = ~128.3 MB)
    float* outF = (float*)d_out;
    float* outG = outF + (size_t)16384 * 256;

    cvt_w<<<4800, 256, 0, stream>>>(Wv, Ws, Wc, in_w, out_w, g1w, w0);
    gemm_ln<<<384, 256, 0, stream>>>(fv, fs, fc, wWv, wWs, wWc,
                                     bv, gv, bev, bs, gs, bes, bc, gc_, bec, stack);
    gemm_qkv<<<dim3(3, 384), 256, 0, stream>>>(stack, wIn, in_b, qkv);
    attn_k<<<2048, 256, 0, stream>>>(qkv, ctx);
    outproj_k<<<1024, 256, 0, stream>>>(ctx, wOut, out_b, stack, gn, gb,
                                        wG1, g1b, g2w, g2b, outF, outG);
}

// Round 6
// 453.932 us; speedup vs baseline: 1.2207x; 1.0218x over previous
//
#include <hip/hip_runtime.h>
#include <math.h>

// GatedCrossAttentionFusion on MI355X (gfx950), bf16 MFMA pipeline.
// B=16384, VD=2048, SD=1024, CD=512, H=256, HEADS=4, DH=64.
//
// Pipeline (all bf16 intermediates in ws):
//  K0 cvt_w     : fp32->bf16 weight conversion (Wv,Ws,Wc,in_w,out_w,g1w)
//  K1 gemm_ln   : {fv,fs,fc} @ W.T + bias -> LayerNorm -> stack (B*3,256) bf16
//  K2 gemm_qkv  : stack @ in_w.T + in_b -> qkv (B*3,768) bf16
//  K3 attn_k    : per-b 4-head 3x3 attention -> ctx (B*3,256) bf16
//  K4 outproj_k : ctx @ out_w.T + out_b + stack -> LN -> gating MLP -> fused+gates
//
// R0-R5 lessons (gemm_ln): time is invariant (~130us) under schedule changes
// (plain/dbuf/counted-vmcnt), occupancy (11-60%), and staged-byte cuts; best
// measured variant is R2's 1-deep dbuf (130.8us) -- kept verbatim. R6 attacks
// the OTHER ~300us: K2 rebuilt with an LDS-resident full-K A-tile (BM=192,
// 256 blocks = 1/CU, in_w staged 98MB vs ~300MB), K4 tile doubled (BM=96,
// halves out_w/g1w re-staging).

typedef unsigned short u16;
typedef __bf16 bf16x8 __attribute__((ext_vector_type(8)));
typedef float fx4 __attribute__((ext_vector_type(4)));

#define MFMA_BF16(A_, B_, C_) __builtin_amdgcn_mfma_f32_16x16x32_bf16((A_), (B_), (C_), 0, 0, 0)

__device__ __forceinline__ float bf2f(u16 s) {
    union { float f; unsigned u; } c; c.u = ((unsigned)s) << 16; return c.f;
}
__device__ __forceinline__ u16 f2bf(float f) {
    union { float f; unsigned u; } c; c.f = f;
    return (u16)((c.u + 0x7fffu + ((c.u >> 16) & 1u)) >> 16);
}
// a,b are packed bf16 pairs (little-endian: low u16 = even element)
__device__ __forceinline__ float bfpair_dot(unsigned a, unsigned b) {
    union { unsigned u; float f; } al, ah, bl, bh;
    al.u = a << 16; ah.u = a & 0xffff0000u;
    bl.u = b << 16; bh.u = b & 0xffff0000u;
    return al.f * bl.f + ah.f * bh.f;
}
__device__ __forceinline__ void gld16(void* l, const void* g) {
    __builtin_amdgcn_global_load_lds((const __attribute__((address_space(1))) void*)g,
                                     (__attribute__((address_space(3))) void*)l, 16, 0, 0);
}

// ---------------------------------------------------------------- K0: weights
__global__ __launch_bounds__(256) void cvt_w(const float* Wv, const float* Ws, const float* Wc,
                                             const float* inw, const float* outw, const float* g1w,
                                             u16* dst) {
    int idx = blockIdx.x * 256 + threadIdx.x;  // grid covers exactly 1228800
    const float* src; int rel;
    if      (idx <  524288) { src = Wv;   rel = idx; }
    else if (idx <  786432) { src = Ws;   rel = idx -  524288; }
    else if (idx <  917504) { src = Wc;   rel = idx -  786432; }
    else if (idx < 1114112) { src = inw;  rel = idx -  917504; }
    else if (idx < 1179648) { src = outw; rel = idx - 1114112; }
    else                    { src = g1w;  rel = idx - 1179648; }
    dst[idx] = f2bf(src[rel]);
}

// ------------------------------------------------- K1: input GEMM + LayerNorm
// R2 variant verbatim (best measured: 130.8us). BM=64, BN=256, BK=32, 4 waves.
// 1D grid of 768 blocks, longest-job-first. Double-buffered LDS + 1-deep
// prefetch, single barrier per K-step.
__global__ __launch_bounds__(256, 3) void gemm_ln(
    const float* fv, const float* fs, const float* fc,
    const u16* wWv, const u16* wWs, const u16* wWc,
    const float* bv, const float* gv, const float* bev,
    const float* bs, const float* gs, const float* bes,
    const float* bc, const float* gc_, const float* bec,
    u16* stack) {
    __shared__ alignas(16) char smem[45568];
    u16* sC = (u16*)smem;
    float* redS = (float*)(smem + 43008);   // [64][4]
    float* redQ = (float*)(smem + 44032);   // [64][4]
    float* mvS  = (float*)(smem + 45056);   // [64][2] mean,rstd

    int bid = blockIdx.x;
    int slot, mblk;
    if (bid < 256)      { slot = 0; mblk = bid; }
    else if (bid < 512) { slot = 1; mblk = bid - 256; }
    else                { slot = 2; mblk = bid - 512; }

    const float* A; const u16* W; const float* bias; const float* gg; const float* be; int K;
    if (slot == 0)      { A = fv; W = wWv; bias = bv; gg = gv;  be = bev; K = 2048; }
    else if (slot == 1) { A = fs; W = wWs; bias = bs; gg = gs;  be = bes; K = 1024; }
    else                { A = fc; W = wWc; bias = bc; gg = gc_; be = bec; K = 512;  }

    int t = threadIdx.x, wv = t >> 6, ln = t & 63, q = ln >> 4, l15 = ln & 15;
    int m0 = mblk * 64;

    fx4 zero = {0.f, 0.f, 0.f, 0.f};
    fx4 acc[4][4];
    #pragma unroll
    for (int mi = 0; mi < 4; ++mi)
        #pragma unroll
        for (int ni = 0; ni < 4; ++ni) acc[mi][ni] = zero;

    int rowA = t >> 2, ca = t & 3;                       // 64 rows x 4 chunks-of-8
    const float* aBase = A + (size_t)(m0 + rowA) * K + ca * 8;
    int sAwOff = rowA * 40 + ca * 8;                     // elem offset within sA buf

    int bN[4], bKc[4], bDst[4];
    #pragma unroll
    for (int i = 0; i < 4; ++i) {
        int d = wv * 256 + i * 64 + ln;
        bN[i] = d >> 2;
        bKc[i] = (d & 3) ^ ((bN[i] >> 1) & 3);
        bDst[i] = (wv * 256 + i * 64) * 16;              // byte offset in sB buf
    }

    int niter = K >> 5;

    // ---- prologue: stage tile 0 into buf 0
    {
        float4 f0 = *(const float4*)(aBase);
        float4 f1 = *(const float4*)(aBase + 4);
        #pragma unroll
        for (int i = 0; i < 4; ++i)
            gld16(smem + 10240 + bDst[i], W + (size_t)bN[i] * K + bKc[i] * 8);
        union { u16 us[8]; uint4 v; } pk;
        pk.us[0] = f2bf(f0.x); pk.us[1] = f2bf(f0.y); pk.us[2] = f2bf(f0.z); pk.us[3] = f2bf(f0.w);
        pk.us[4] = f2bf(f1.x); pk.us[5] = f2bf(f1.y); pk.us[6] = f2bf(f1.z); pk.us[7] = f2bf(f1.w);
        *(uint4*)((u16*)smem + sAwOff) = pk.v;
    }
    __syncthreads();

    for (int kt = 0; kt < niter; ++kt) {
        int cur = kt & 1, nxt_b = (kt + 1) & 1;
        u16* sAc = (u16*)(smem + cur * 5120);
        u16* sBc = (u16*)(smem + 10240 + cur * 16384);
        int has_next = (kt + 1) < niter;

        float4 nf0, nf1;
        if (has_next) {
            nf0 = *(const float4*)(aBase + (kt + 1) * 32);
            nf1 = *(const float4*)(aBase + (kt + 1) * 32 + 4);
            char* sBn = smem + 10240 + nxt_b * 16384;
            #pragma unroll
            for (int i = 0; i < 4; ++i)
                gld16(sBn + bDst[i], W + (size_t)bN[i] * K + (kt + 1) * 32 + bKc[i] * 8);
        }

        bf16x8 af[4], bfr[4];
        #pragma unroll
        for (int mi = 0; mi < 4; ++mi)
            af[mi] = *(const bf16x8*)(sAc + (mi * 16 + l15) * 40 + q * 8);
        #pragma unroll
        for (int ni = 0; ni < 4; ++ni) {
            int n = wv * 64 + ni * 16 + l15;
            int ch = n * 4 + (q ^ ((n >> 1) & 3));
            bfr[ni] = *(const bf16x8*)(sBc + ch * 8);
        }
        #pragma unroll
        for (int mi = 0; mi < 4; ++mi)
            #pragma unroll
            for (int ni = 0; ni < 4; ++ni)
                acc[mi][ni] = MFMA_BF16(af[mi], bfr[ni], acc[mi][ni]);

        if (has_next) {
            union { u16 us[8]; uint4 v; } pk;
            pk.us[0] = f2bf(nf0.x); pk.us[1] = f2bf(nf0.y); pk.us[2] = f2bf(nf0.z); pk.us[3] = f2bf(nf0.w);
            pk.us[4] = f2bf(nf1.x); pk.us[5] = f2bf(nf1.y); pk.us[6] = f2bf(nf1.z); pk.us[7] = f2bf(nf1.w);
            *(uint4*)((u16*)(smem + nxt_b * 5120) + sAwOff) = pk.v;
        }
        __syncthreads();
    }

    // epilogue: bias, LN stats from registers, normalize, write bf16
    float biasv[4], gvv[4], bevv[4];
    #pragma unroll
    for (int ni = 0; ni < 4; ++ni) {
        int col = wv * 64 + ni * 16 + l15;
        biasv[ni] = bias[col]; gvv[ni] = gg[col]; bevv[ni] = be[col];
    }
    #pragma unroll
    for (int mi = 0; mi < 4; ++mi)
        #pragma unroll
        for (int ni = 0; ni < 4; ++ni)
            #pragma unroll
            for (int r = 0; r < 4; ++r) acc[mi][ni][r] += biasv[ni];
    #pragma unroll
    for (int mi = 0; mi < 4; ++mi) {
        #pragma unroll
        for (int r = 0; r < 4; ++r) {
            float s = 0.f, qq = 0.f;
            #pragma unroll
            for (int ni = 0; ni < 4; ++ni) { float x = acc[mi][ni][r]; s += x; qq += x * x; }
            #pragma unroll
            for (int m = 1; m < 16; m <<= 1) { s += __shfl_xor(s, m, 64); qq += __shfl_xor(qq, m, 64); }
            if (l15 == 0) { int rho = mi * 16 + q * 4 + r; redS[rho * 4 + wv] = s; redQ[rho * 4 + wv] = qq; }
        }
    }
    __syncthreads();
    if (t < 64) {
        float s = redS[t * 4] + redS[t * 4 + 1] + redS[t * 4 + 2] + redS[t * 4 + 3];
        float qq = redQ[t * 4] + redQ[t * 4 + 1] + redQ[t * 4 + 2] + redQ[t * 4 + 3];
        float mean = s * (1.f / 256.f);
        float var = qq * (1.f / 256.f) - mean * mean;
        mvS[t * 2] = mean; mvS[t * 2 + 1] = rsqrtf(var + 1e-5f);
    }
    __syncthreads();
    #pragma unroll
    for (int mi = 0; mi < 4; ++mi) {
        #pragma unroll
        for (int r = 0; r < 4; ++r) {
            int rho = mi * 16 + q * 4 + r;
            float mean = mvS[rho * 2], rstd = mvS[rho * 2 + 1];
            #pragma unroll
            for (int ni = 0; ni < 4; ++ni) {
                int col = wv * 64 + ni * 16 + l15;
                float x = (acc[mi][ni][r] - mean) * rstd * gvv[ni] + bevv[ni];
                sC[rho * 256 + col] = f2bf(x);
            }
        }
    }
    __syncthreads();
    u16* outp = stack + (size_t)m0 * 768 + slot * 256;
    #pragma unroll
    for (int it = 0; it < 8; ++it) {
        int idx = t + it * 256;
        int row = idx >> 5, c = idx & 31;
        uint4 v = *(const uint4*)(sC + row * 256 + c * 8);
        *(uint4*)(outp + (size_t)row * 768 + c * 8) = v;
    }
}

// ------------------------------------------------------ K2: qkv = stack@in_w.T
// M=49152, K=256, N=768. BM=192 (256 blocks = 1/CU exactly), 512 threads
// (8 waves: wr=wv>>1 owns rows wr*48..+47, wc=wv&1 owns 128 cols of the
// current 256-col panel-pair). Full-K A-tile (192x256 bf16 = 96KB) resident in
// LDS, staged ONCE (XOR-32 swizzle). 3 N-panel-pairs x 8 K-steps; only the
// 16KB in_w k-slice is staged per step (double-buffered, 1 barrier/step).
__global__ __launch_bounds__(512, 2) void gemm_qkv(const u16* stack, const u16* W, const float* in_b,
                                                   u16* qkv) {
    // sA @0 (98304B: 6144 chunks, row r pos p holds k-chunk p^(r&31))
    // sB dbuf @98304 + buf*16384 ; sC bounce @131072 (48 x 264 u16 = 25344B)
    __shared__ alignas(16) char smem[156416];
    u16* sA = (u16*)smem;
    u16* sC = (u16*)(smem + 131072);

    int t = threadIdx.x, wv = t >> 6, ln = t & 63, q = ln >> 4, l15 = ln & 15;
    int wr = wv >> 1, wc = wv & 1;
    int m0 = blockIdx.x * 192;

    // stage resident A tile: 12 chunks/thread
    #pragma unroll
    for (int i = 0; i < 12; ++i) {
        int d = i * 512 + t;
        int r = d >> 5, p = d & 31;
        int kc = p ^ (r & 31);
        gld16((char*)smem + d * 16, stack + (size_t)(m0 + r) * 256 + kc * 8);
    }
    // B staging maps (2 chunks/thread, pos p of row n holds k-chunk p^((n>>1)&3))
    int bN[2], bKc[2];
    #pragma unroll
    for (int i = 0; i < 2; ++i) {
        int d = i * 512 + t;
        bN[i] = d >> 2;
        bKc[i] = (d & 3) ^ ((bN[i] >> 1) & 3);
    }

#define QK_STAGE(sstep)                                                              \
    {                                                                                \
        int np_ = (sstep) >> 3, kt_ = (sstep) & 7;                                   \
        char* dst_ = smem + 98304 + ((sstep) & 1) * 16384;                           \
        _Pragma("unroll")                                                            \
        for (int i_ = 0; i_ < 2; ++i_)                                               \
            gld16(dst_ + (i_ * 512 + t) * 16,                                        \
                  W + (size_t)(np_ * 256 + bN[i_]) * 256 + kt_ * 32 + bKc[i_] * 8);  \
    }

    QK_STAGE(0);
    __syncthreads();   // A tile + first B slice ready

    fx4 zero = {0.f, 0.f, 0.f, 0.f};
    for (int np = 0; np < 3; ++np) {
        fx4 acc[3][8];
        #pragma unroll
        for (int mi = 0; mi < 3; ++mi)
            #pragma unroll
            for (int ni = 0; ni < 8; ++ni) acc[mi][ni] = zero;

        for (int kt = 0; kt < 8; ++kt) {
            int s = np * 8 + kt;
            if (s + 1 < 24) QK_STAGE(s + 1);
            const u16* sBc = (const u16*)(smem + 98304 + (s & 1) * 16384);
            bf16x8 af[3], bfr[8];
            #pragma unroll
            for (int mi = 0; mi < 3; ++mi) {
                int row = wr * 48 + mi * 16 + l15;
                int ck = kt * 4 + q;
                af[mi] = *(const bf16x8*)(sA + (row * 32 + (ck ^ (row & 31))) * 8);
            }
            #pragma unroll
            for (int ni = 0; ni < 8; ++ni) {
                int n = wc * 128 + ni * 16 + l15;
                int ch = n * 4 + (q ^ ((n >> 1) & 3));
                bfr[ni] = *(const bf16x8*)(sBc + ch * 8);
            }
            #pragma unroll
            for (int mi = 0; mi < 3; ++mi)
                #pragma unroll
                for (int ni = 0; ni < 8; ++ni)
                    acc[mi][ni] = MFMA_BF16(af[mi], bfr[ni], acc[mi][ni]);
            __syncthreads();   // drains next-slice DMA + readers of current buf
        }

        // epilogue for panel-pair np: bias + bounce through sC in 4 row-rounds
        float biasv[8];
        #pragma unroll
        for (int ni = 0; ni < 8; ++ni) biasv[ni] = in_b[np * 256 + wc * 128 + ni * 16 + l15];
        #pragma unroll
        for (int g = 0; g < 4; ++g) {
            if (wr == g) {
                #pragma unroll
                for (int mi = 0; mi < 3; ++mi)
                    #pragma unroll
                    for (int ni = 0; ni < 8; ++ni)
                        #pragma unroll
                        for (int r = 0; r < 4; ++r) {
                            int lr = mi * 16 + q * 4 + r;
                            int cl = wc * 128 + ni * 16 + l15;
                            sC[lr * 264 + cl] = f2bf(acc[mi][ni][r] + biasv[ni]);
                        }
            }
            __syncthreads();
            #pragma unroll
            for (int i = 0; i < 3; ++i) {
                int idx = i * 512 + t;
                int row = idx >> 5, c = idx & 31;
                uint4 v = *(const uint4*)(sC + row * 264 + c * 8);
                *(uint4*)(qkv + (size_t)(m0 + g * 48 + row) * 768 + np * 256 + c * 8) = v;
            }
            __syncthreads();
        }
    }
#undef QK_STAGE
}

// ------------------------------------------------------------- K3: attention
// 8 b's per block. qkv row per (b,i): [q(256)|k(256)|v(256)].
__global__ __launch_bounds__(256) void attn_k(const u16* qkv, u16* ctx) {
    __shared__ alignas(16) char smem[38016];
    u16* qs = (u16*)smem;                 // 8*2304 bf16
    float* sS = (float*)(smem + 36864);   // 288 scores/probs: [b][h][i][j]

    int t = threadIdx.x, wv = t >> 6, ln = t & 63;
    size_t base = (size_t)blockIdx.x * 8 * 2304;
    #pragma unroll
    for (int i = 0; i < 9; ++i) {
        int d = wv * 576 + i * 64;
        gld16((char*)smem + (size_t)d * 16, qkv + base + (size_t)(d + ln) * 8);
    }
    __syncthreads();
    // scores: 288 items = 8b*4h*9(i,j)
    #pragma unroll
    for (int it = 0; it < 2; ++it) {
        int idx = t + it * 256;
        if (idx < 288) {
            int b = idx / 36, rem = idx % 36, h = rem / 9, pp = rem % 9, i = pp / 3, j = pp % 3;
            const u16* qp = qs + b * 2304 + i * 768 + h * 64;
            const u16* kp = qs + b * 2304 + j * 768 + 256 + h * 64;
            float acc = 0.f;
            #pragma unroll
            for (int c = 0; c < 8; ++c) {
                uint4 qa = *(const uint4*)(qp + c * 8);
                uint4 ka = *(const uint4*)(kp + c * 8);
                acc += bfpair_dot(qa.x, ka.x) + bfpair_dot(qa.y, ka.y) +
                       bfpair_dot(qa.z, ka.z) + bfpair_dot(qa.w, ka.w);
            }
            sS[idx] = acc * 0.125f;  // /sqrt(64)
        }
    }
    __syncthreads();
    if (t < 96) {  // softmax over j, t = b*12 + h*3 + i
        int b3 = t * 3;
        float s0 = sS[b3], s1 = sS[b3 + 1], s2 = sS[b3 + 2];
        float m = fmaxf(s0, fmaxf(s1, s2));
        float e0 = __expf(s0 - m), e1 = __expf(s1 - m), e2 = __expf(s2 - m);
        float inv = 1.f / (e0 + e1 + e2);
        sS[b3] = e0 * inv; sS[b3 + 1] = e1 * inv; sS[b3 + 2] = e2 * inv;
    }
    __syncthreads();
    // ctx: 768 items = 8b * 3i * 32 chunks-of-8
    #pragma unroll
    for (int it = 0; it < 3; ++it) {
        int idx = t + it * 256;
        int b = idx / 96, rem = idx % 96, i = rem / 32, c = rem & 31, h = c >> 3;
        int pbase = b * 36 + h * 9 + i * 3;
        float o[8];
        #pragma unroll
        for (int e = 0; e < 8; ++e) o[e] = 0.f;
        #pragma unroll
        for (int j = 0; j < 3; ++j) {
            float p = sS[pbase + j];
            uint4 va = *(const uint4*)(qs + b * 2304 + j * 768 + 512 + c * 8);
            unsigned uu[4] = {va.x, va.y, va.z, va.w};
            #pragma unroll
            for (int pr = 0; pr < 4; ++pr) {
                union { unsigned u; float f; } lo, hi;
                lo.u = uu[pr] << 16; hi.u = uu[pr] & 0xffff0000u;
                o[2 * pr]     += p * lo.f;
                o[2 * pr + 1] += p * hi.f;
            }
        }
        union { u16 us[8]; uint4 v; } pk;
        #pragma unroll
        for (int e = 0; e < 8; ++e) pk.us[e] = f2bf(o[e]);
        *(uint4*)(ctx + (size_t)(blockIdx.x * 8 + b) * 768 + i * 256 + c * 8) = pk.v;
    }
}

// -------------------- K4: out-proj + residual + LN + gating MLP + fused output
// BM=96 (32 b's, 512 blocks -- halves out_w/g1w re-staging vs BM=48), BN=256,
// K=256. region1: ctxA -> stackS -> rowBuf(attended,swizzled)
__global__ __launch_bounds__(256) void outproj_k(
    const u16* ctx, const u16* W, const float* out_b, const u16* stack,
    const float* gn, const float* gb, const u16* g1w, const float* g1b,
    const float* g2w, const float* g2b, float* outF, float* outG) {
    __shared__ alignas(16) char smem[65536];
    u16* r1 = (u16*)smem;                         // 96x256 bf16 = 49152B
    u16* sB = (u16*)(smem + 49152);               // 16384B (k-loop)
    float* redS = (float*)(smem + 49152);         // [96][4] (overlay sB post-loop)
    float* redQ = (float*)(smem + 50688);         // [96][4]
    float* mvS  = (float*)(smem + 52224);         // [96][2]
    float* h1S  = (float*)(smem + 53248);         // [32][64]
    float* lgS  = (float*)(smem + 61440);         // 96 logits
    float* gateS= (float*)(smem + 61824);         // 96 gates

    int t = threadIdx.x, wv = t >> 6, ln = t & 63, q = ln >> 4, l15 = ln & 15;
    int gr0 = blockIdx.x * 96, b0 = blockIdx.x * 32;

    // stage full ctx tile [96][256], 3072 chunks (12/thread), pos p of row
    // holds k-chunk p^(row&7)
    #pragma unroll
    for (int i = 0; i < 12; ++i) {
        int d = i * 256 + t;
        int row = d >> 5, p = d & 31;
        int kc = p ^ (row & 7);
        gld16((char*)r1 + d * 16, ctx + (size_t)(gr0 + row) * 256 + kc * 8);
    }
    __syncthreads();

    fx4 zero = {0.f, 0.f, 0.f, 0.f};
    fx4 acc[6][4];
    #pragma unroll
    for (int mi = 0; mi < 6; ++mi)
        #pragma unroll
        for (int ni = 0; ni < 4; ++ni) acc[mi][ni] = zero;

    for (int kt = 0; kt < 8; ++kt) {
        #pragma unroll
        for (int i = 0; i < 4; ++i) {
            int d = i * 256 + t;
            int n = d >> 2, p = d & 3;
            int kc = p ^ ((n >> 1) & 3);
            gld16((char*)sB + d * 16, W + (size_t)n * 256 + kt * 32 + kc * 8);
        }
        __syncthreads();
        bf16x8 af[6], bfr[4];
        #pragma unroll
        for (int mi = 0; mi < 6; ++mi) {
            int row = mi * 16 + l15;
            int ch = row * 32 + ((kt * 4 + q) ^ (row & 7));
            af[mi] = *(const bf16x8*)(r1 + ch * 8);
        }
        #pragma unroll
        for (int ni = 0; ni < 4; ++ni) {
            int n = wv * 64 + ni * 16 + l15;
            int ch = n * 4 + (q ^ ((n >> 1) & 3));
            bfr[ni] = *(const bf16x8*)(sB + ch * 8);
        }
        #pragma unroll
        for (int mi = 0; mi < 6; ++mi)
            #pragma unroll
            for (int ni = 0; ni < 4; ++ni)
                acc[mi][ni] = MFMA_BF16(af[mi], bfr[ni], acc[mi][ni]);
        __syncthreads();
    }

    // stage stack tile [96][256] (contiguous in global) into r1
    #pragma unroll
    for (int i = 0; i < 12; ++i) {
        int d = i * 256 + t;
        gld16((char*)r1 + d * 16, stack + (size_t)gr0 * 256 + (size_t)d * 8);
    }
    __syncthreads();

    float obv[4], gnv[4], gbv[4];
    #pragma unroll
    for (int ni = 0; ni < 4; ++ni) {
        int col = wv * 64 + ni * 16 + l15;
        obv[ni] = out_b[col]; gnv[ni] = gn[col]; gbv[ni] = gb[col];
    }
    #pragma unroll
    for (int mi = 0; mi < 6; ++mi)
        #pragma unroll
        for (int ni = 0; ni < 4; ++ni)
            #pragma unroll
            for (int r = 0; r < 4; ++r) {
                int rho = mi * 16 + q * 4 + r;
                int col = wv * 64 + ni * 16 + l15;
                acc[mi][ni][r] += obv[ni] + bf2f(r1[rho * 256 + col]);
            }
    // LN stats
    #pragma unroll
    for (int mi = 0; mi < 6; ++mi) {
        #pragma unroll
        for (int r = 0; r < 4; ++r) {
            float s = 0.f, qq = 0.f;
            #pragma unroll
            for (int ni = 0; ni < 4; ++ni) { float x = acc[mi][ni][r]; s += x; qq += x * x; }
            #pragma unroll
            for (int m = 1; m < 16; m <<= 1) { s += __shfl_xor(s, m, 64); qq += __shfl_xor(qq, m, 64); }
            if (l15 == 0) { int rho = mi * 16 + q * 4 + r; redS[rho * 4 + wv] = s; redQ[rho * 4 + wv] = qq; }
        }
    }
    __syncthreads();
    if (t < 96) {
        float s = redS[t * 4] + redS[t * 4 + 1] + redS[t * 4 + 2] + redS[t * 4 + 3];
        float qq = redQ[t * 4] + redQ[t * 4 + 1] + redQ[t * 4 + 2] + redQ[t * 4 + 3];
        float mean = s * (1.f / 256.f);
        float var = qq * (1.f / 256.f) - mean * mean;
        mvS[t * 2] = mean; mvS[t * 2 + 1] = rsqrtf(var + 1e-5f);
    }
    __syncthreads();
    // normalize -> rowBuf (r1, swizzled as [32 b][96 chunks], chunk = bl*96 + (kidx^(bl&7)))
    #pragma unroll
    for (int mi = 0; mi < 6; ++mi) {
        #pragma unroll
        for (int r = 0; r < 4; ++r) {
            int rho = mi * 16 + q * 4 + r;
            float mean = mvS[rho * 2], rstd = mvS[rho * 2 + 1];
            int bl = rho / 3, sl = rho - bl * 3;
            #pragma unroll
            for (int ni = 0; ni < 4; ++ni) {
                int col = wv * 64 + ni * 16 + l15;
                float x = (acc[mi][ni][r] - mean) * rstd * gnv[ni] + gbv[ni];
                int k = sl * 256 + col;
                int kidx = k >> 3, wn = k & 7;
                r1[(bl * 96 + (kidx ^ (bl & 7))) * 8 + wn] = f2bf(x);
            }
        }
    }
    __syncthreads();
    // gating MFMA: h1[32 b][64] = attended_flat(32x768) @ g1w.T in two 16-b
    // halves sharing the g1w fragment; wave wv owns cols wv*16..+15
    fx4 ag0 = zero, ag1 = zero;
    for (int kt = 0; kt < 24; ++kt) {
        int kidx = kt * 4 + q;
        int n = wv * 16 + l15;
        bf16x8 bfr2 = *(const bf16x8*)(g1w + (size_t)n * 768 + kt * 32 + q * 8);
        bf16x8 a0 = *(const bf16x8*)(r1 + (l15 * 96 + (kidx ^ (l15 & 7))) * 8);
        bf16x8 a1 = *(const bf16x8*)(r1 + ((16 + l15) * 96 + (kidx ^ (l15 & 7))) * 8);
        ag0 = MFMA_BF16(a0, bfr2, ag0);
        ag1 = MFMA_BF16(a1, bfr2, ag1);
    }
    #pragma unroll
    for (int r = 0; r < 4; ++r) {
        int bl = q * 4 + r, n = wv * 16 + l15;
        float x0 = ag0[r] + g1b[n];
        float x1 = ag1[r] + g1b[n];
        h1S[bl * 64 + n]        = 0.5f * x0 * (1.f + erff(x0 * 0.70710678118f));
        h1S[(16 + bl) * 64 + n] = 0.5f * x1 * (1.f + erff(x1 * 0.70710678118f));
    }
    __syncthreads();
    if (t < 96) {  // logits: t = bl*3 + s
        int bl = t / 3, s = t - bl * 3;
        float a = g2b[s];
        #pragma unroll
        for (int k = 0; k < 64; ++k) a += h1S[bl * 64 + k] * g2w[s * 64 + k];
        lgS[t] = a;
    }
    __syncthreads();
    if (t < 96) {
        int bl = t / 3, s = t - bl * 3;
        float l0 = lgS[bl * 3], l1 = lgS[bl * 3 + 1], l2 = lgS[bl * 3 + 2];
        float m = fmaxf(l0, fmaxf(l1, l2));
        float e0 = __expf(l0 - m), e1 = __expf(l1 - m), e2 = __expf(l2 - m);
        float inv = 1.f / (e0 + e1 + e2);
        float gsel = ((s == 0) ? e0 : (s == 1) ? e1 : e2) * inv;
        gateS[t] = gsel;
        outG[(size_t)(b0 + bl) * 3 + s] = gsel;
    }
    __syncthreads();
    // fused = sum_s gate[s] * attended[s] : 32 b x 32 chunks = 1024 items
    #pragma unroll
    for (int it = 0; it < 4; ++it) {
        int idx = t + it * 256;
        int b = idx >> 5, c = idx & 31;
        float g0 = gateS[b * 3], g1 = gateS[b * 3 + 1], g2 = gateS[b * 3 + 2];
        float o[8];
        #pragma unroll
        for (int e = 0; e < 8; ++e) o[e] = 0.f;
        #pragma unroll
        for (int s = 0; s < 3; ++s) {
            float gw = (s == 0) ? g0 : (s == 1) ? g1 : g2;
            int kidx = s * 32 + c;
            uint4 raw = *(const uint4*)(r1 + (b * 96 + (kidx ^ (b & 7))) * 8);
            unsigned uu[4] = {raw.x, raw.y, raw.z, raw.w};
            #pragma unroll
            for (int pr = 0; pr < 4; ++pr) {
                union { unsigned u; float f; } lo, hi;
                lo.u = uu[pr] << 16; hi.u = uu[pr] & 0xffff0000u;
                o[2 * pr]     += gw * lo.f;
                o[2 * pr + 1] += gw * hi.f;
            }
        }
        float* op = outF + (size_t)(b0 + b) * 256 + c * 8;
        float4 v0; v0.x = o[0]; v0.y = o[1]; v0.z = o[2]; v0.w = o[3];
        float4 v1; v1.x = o[4]; v1.y = o[5]; v1.z = o[6]; v1.w = o[7];
        *(float4*)op = v0;
        *(float4*)(op + 4) = v1;
    }
}

extern "C" void kernel_launch(void* const* d_in, const int* in_sizes, int n_in,
                              void* d_out, int out_size, void* d_ws, size_t ws_size,
                              hipStream_t stream) {
    (void)in_sizes; (void)n_in; (void)out_size; (void)ws_size;
    const float* fv   = (const float*)d_in[0];
    const float* fs   = (const float*)d_in[1];
    const float* fc   = (const float*)d_in[2];
    const float* Wv   = (const float*)d_in[3];
    const float* bv   = (const float*)d_in[4];
    const float* gv   = (const float*)d_in[5];
    const float* bev  = (const float*)d_in[6];
    const float* Ws   = (const float*)d_in[7];
    const float* bs   = (const float*)d_in[8];
    const float* gs   = (const float*)d_in[9];
    const float* bes  = (const float*)d_in[10];
    const float* Wc   = (const float*)d_in[11];
    const float* bc   = (const float*)d_in[12];
    const float* gc_  = (const float*)d_in[13];
    const float* bec  = (const float*)d_in[14];
    const float* in_w = (const float*)d_in[15];
    const float* in_b = (const float*)d_in[16];
    const float* out_w= (const float*)d_in[17];
    const float* out_b= (const float*)d_in[18];
    const float* gn   = (const float*)d_in[19];
    const float* gb   = (const float*)d_in[20];
    const float* g1w  = (const float*)d_in[21];
    const float* g1b  = (const float*)d_in[22];
    const float* g2w  = (const float*)d_in[23];
    const float* g2b  = (const float*)d_in[24];

    u16* w0    = (u16*)d_ws;
    u16* wWv   = w0;               // 524288
    u16* wWs   = w0 + 524288;      // 262144
    u16* wWc   = w0 + 786432;      // 131072
    u16* wIn   = w0 + 917504;      // 196608
    u16* wOut  = w0 + 1114112;     // 65536
    u16* wG1   = w0 + 1179648;     // 49152
    u16* stack = w0 + 1228800;     // 49152*256
    u16* qkv   = w0 + 13811712;    // 49152*768
    u16* ctx   = w0 + 51560448;    // 49152*256  (total 64143360 u16 = ~128.3 MB)
    float* outF = (float*)d_out;
    float* outG = outF + (size_t)16384 * 256;

    cvt_w<<<4800, 256, 0, stream>>>(Wv, Ws, Wc, in_w, out_w, g1w, w0);
    gemm_ln<<<768, 256, 0, stream>>>(fv, fs, fc, wWv, wWs, wWc,
                                     bv, gv, bev, bs, gs, bes, bc, gc_, bec, stack);
    gemm_qkv<<<256, 512, 0, stream>>>(stack, wIn, in_b, qkv);
    attn_k<<<2048, 256, 0, stream>>>(qkv, ctx);
    outproj_k<<<512, 256, 0, stream>>>(ctx, wOut, out_b, stack, gn, gb,
                                       wG1, g1b, g2w, g2b, outF, outG);
}

// Round 7
// 435.875 us; speedup vs baseline: 1.2713x; 1.0414x over previous
//
#include <hip/hip_runtime.h>
#include <math.h>

// GatedCrossAttentionFusion on MI355X (gfx950), bf16 MFMA pipeline.
// B=16384, VD=2048, SD=1024, CD=512, H=256, HEADS=4, DH=64.
//
// Pipeline (all bf16 intermediates in ws):
//  K0 cvt_w     : fp32->bf16 weight conversion (Wv,Ws,Wc,in_w,out_w,g1w)
//  K1 gemm_ln   : {fv,fs,fc} @ W.T + bias -> LayerNorm -> stack (B*3,256) bf16
//  K2 gemm_qkv  : stack @ in_w.T + in_b -> qkv (B*3,768) bf16
//  K3 attn_k    : per-b 4-head 3x3 attention -> ctx (B*3,256) bf16
//  K4 outproj_k : ctx @ out_w.T + out_b + stack -> LN -> gating MLP -> fused+gates
//
// R0-R6 ledger: K1 step-period model (two-point fit R2/R5): per-K-step cost ~
// 2550 cyc fixed + ~94 cyc/KB staged -> fixed part is 53% at BK=32. R7: K1
// BK=64 halves step count (predicted ~94us). K2/K4 are R3's variants verbatim
// (best measured e2e = 430; R6's resident-A/BM-96 rebuilds were ~25us worse).

typedef unsigned short u16;
typedef __bf16 bf16x8 __attribute__((ext_vector_type(8)));
typedef float fx4 __attribute__((ext_vector_type(4)));

#define MFMA_BF16(A_, B_, C_) __builtin_amdgcn_mfma_f32_16x16x32_bf16((A_), (B_), (C_), 0, 0, 0)
#define WAIT_VM(N) asm volatile("s_waitcnt vmcnt(" #N ")" ::: "memory")

__device__ __forceinline__ float bf2f(u16 s) {
    union { float f; unsigned u; } c; c.u = ((unsigned)s) << 16; return c.f;
}
__device__ __forceinline__ u16 f2bf(float f) {
    union { float f; unsigned u; } c; c.f = f;
    return (u16)((c.u + 0x7fffu + ((c.u >> 16) & 1u)) >> 16);
}
// a,b are packed bf16 pairs (little-endian: low u16 = even element)
__device__ __forceinline__ float bfpair_dot(unsigned a, unsigned b) {
    union { unsigned u; float f; } al, ah, bl, bh;
    al.u = a << 16; ah.u = a & 0xffff0000u;
    bl.u = b << 16; bh.u = b & 0xffff0000u;
    return al.f * bl.f + ah.f * bh.f;
}
__device__ __forceinline__ void gld16(void* l, const void* g) {
    __builtin_amdgcn_global_load_lds((const __attribute__((address_space(1))) void*)g,
                                     (__attribute__((address_space(3))) void*)l, 16, 0, 0);
}

// ---------------------------------------------------------------- K0: weights
__global__ __launch_bounds__(256) void cvt_w(const float* Wv, const float* Ws, const float* Wc,
                                             const float* inw, const float* outw, const float* g1w,
                                             u16* dst) {
    int idx = blockIdx.x * 256 + threadIdx.x;  // grid covers exactly 1228800
    const float* src; int rel;
    if      (idx <  524288) { src = Wv;   rel = idx; }
    else if (idx <  786432) { src = Ws;   rel = idx -  524288; }
    else if (idx <  917504) { src = Wc;   rel = idx -  786432; }
    else if (idx < 1114112) { src = inw;  rel = idx -  917504; }
    else if (idx < 1179648) { src = outw; rel = idx - 1114112; }
    else                    { src = g1w;  rel = idx - 1179648; }
    dst[idx] = f2bf(src[rel]);
}

// ------------------------------------------------- K1: input GEMM + LayerNorm
// BM=64, BN=256(=H), BK=64 (32 MFMA/step), 4 waves (wave w owns cols w*64..+63).
// 1D grid of 768 blocks, longest-job-first (bid<256 slot0 K=2048, <512 slot1,
// else slot2). R2's double-buffered 1-deep-prefetch 1-barrier schedule, with
// BK doubled 32->64: halves the step count (the ~2550-cyc fixed per-step cost
// was 53% of K1's time at BK=32). LDS ~86KB -> 1 block/CU (occupancy proven
// irrelevant for this kernel in R1/R5).
__global__ __launch_bounds__(256) void gemm_ln(
    const float* fv, const float* fs, const float* fc,
    const u16* wWv, const u16* wWs, const u16* wWc,
    const float* bv, const float* gv, const float* bev,
    const float* bs, const float* gs, const float* bes,
    const float* bc, const float* gc_, const float* bec,
    u16* stack) {
    // sA dbuf @0/9216 ([64][72] bf16 each), sB dbuf @18432/51200 (32KB each,
    // 2048 x16B chunks, slot p of row n holds k-chunk p^(n&7)),
    // sC epilogue overlay @0 (32KB), red arrays @83968.
    __shared__ alignas(16) char smem[86528];
    u16* sC = (u16*)smem;
    float* redS = (float*)(smem + 83968);   // [64][4]
    float* redQ = (float*)(smem + 84992);   // [64][4]
    float* mvS  = (float*)(smem + 86016);   // [64][2] mean,rstd

    int bid = blockIdx.x;
    int slot, mblk;
    if (bid < 256)      { slot = 0; mblk = bid; }
    else if (bid < 512) { slot = 1; mblk = bid - 256; }
    else                { slot = 2; mblk = bid - 512; }

    const float* A; const u16* W; const float* bias; const float* gg; const float* be; int K;
    if (slot == 0)      { A = fv; W = wWv; bias = bv; gg = gv;  be = bev; K = 2048; }
    else if (slot == 1) { A = fs; W = wWs; bias = bs; gg = gs;  be = bes; K = 1024; }
    else                { A = fc; W = wWc; bias = bc; gg = gc_; be = bec; K = 512;  }

    int t = threadIdx.x, wv = t >> 6, ln = t & 63, q = ln >> 4, l15 = ln & 15;
    int m0 = mblk * 64;

    fx4 zero = {0.f, 0.f, 0.f, 0.f};
    fx4 acc[4][4];
    #pragma unroll
    for (int mi = 0; mi < 4; ++mi)
        #pragma unroll
        for (int ni = 0; ni < 4; ++ni) acc[mi][ni] = zero;

    // A staging: 64 rows x 64 fp32/step; thread t handles row t>>2, 16 floats
    int rowA = t >> 2, ca = t & 3;
    const float* aBase = A + (size_t)(m0 + rowA) * K + ca * 16;
    int sAwOff = rowA * 72 + ca * 16;                    // elem offset within sA buf

    // B staging: 2048 x16B chunks/buf; chunk d: row n=d>>3, pos p=d&7 holds
    // global k-chunk p^(n&7). 8 chunks/thread.
    int bN[8], bKc[8], bDst[8];
    #pragma unroll
    for (int i = 0; i < 8; ++i) {
        int d = i * 256 + t;
        bN[i] = d >> 3;
        bKc[i] = (d & 7) ^ (bN[i] & 7);
        bDst[i] = d * 16;                                // byte offset in sB buf
    }

    int niter = K >> 6;   // 32 / 16 / 8

    // ---- prologue: stage tile 0 into buf 0
    {
        float4 f0 = *(const float4*)(aBase);
        float4 f1 = *(const float4*)(aBase + 4);
        float4 f2 = *(const float4*)(aBase + 8);
        float4 f3 = *(const float4*)(aBase + 12);
        #pragma unroll
        for (int i = 0; i < 8; ++i)
            gld16(smem + 18432 + bDst[i], W + (size_t)bN[i] * K + bKc[i] * 8);
        union { u16 us[8]; uint4 v; } p0, p1;
        p0.us[0] = f2bf(f0.x); p0.us[1] = f2bf(f0.y); p0.us[2] = f2bf(f0.z); p0.us[3] = f2bf(f0.w);
        p0.us[4] = f2bf(f1.x); p0.us[5] = f2bf(f1.y); p0.us[6] = f2bf(f1.z); p0.us[7] = f2bf(f1.w);
        p1.us[0] = f2bf(f2.x); p1.us[1] = f2bf(f2.y); p1.us[2] = f2bf(f2.z); p1.us[3] = f2bf(f2.w);
        p1.us[4] = f2bf(f3.x); p1.us[5] = f2bf(f3.y); p1.us[6] = f2bf(f3.z); p1.us[7] = f2bf(f3.w);
        *(uint4*)((u16*)smem + sAwOff) = p0.v;
        *(uint4*)((u16*)smem + sAwOff + 8) = p1.v;
    }
    __syncthreads();

    for (int kt = 0; kt < niter; ++kt) {
        int cur = kt & 1, nxt_b = (kt + 1) & 1;
        u16* sAc = (u16*)(smem + cur * 9216);
        u16* sBc = (u16*)(smem + 18432 + cur * 32768);
        int has_next = (kt + 1) < niter;

        float4 nf0, nf1, nf2, nf3;
        if (has_next) {
            // issue A(t+1) global->reg FIRST, then B(t+1) DMA to the other buf
            nf0 = *(const float4*)(aBase + (kt + 1) * 64);
            nf1 = *(const float4*)(aBase + (kt + 1) * 64 + 4);
            nf2 = *(const float4*)(aBase + (kt + 1) * 64 + 8);
            nf3 = *(const float4*)(aBase + (kt + 1) * 64 + 12);
            char* sBn = smem + 18432 + nxt_b * 32768;
            #pragma unroll
            for (int i = 0; i < 8; ++i)
                gld16(sBn + bDst[i], W + (size_t)bN[i] * K + (kt + 1) * 64 + bKc[i] * 8);
        }

        // compute tile kt from buf[cur]: 2 sub-k groups of 16 MFMA
        #pragma unroll
        for (int kk = 0; kk < 2; ++kk) {
            bf16x8 af[4], bfr[4];
            #pragma unroll
            for (int mi = 0; mi < 4; ++mi)
                af[mi] = *(const bf16x8*)(sAc + (mi * 16 + l15) * 72 + kk * 32 + q * 8);
            #pragma unroll
            for (int ni = 0; ni < 4; ++ni) {
                int n = wv * 64 + ni * 16 + l15;
                int slotc = (kk * 4 + q) ^ (n & 7);
                bfr[ni] = *(const bf16x8*)(sBc + (n * 8 + slotc) * 8);
            }
            #pragma unroll
            for (int mi = 0; mi < 4; ++mi)
                #pragma unroll
                for (int ni = 0; ni < 4; ++ni)
                    acc[mi][ni] = MFMA_BF16(af[mi], bfr[ni], acc[mi][ni]);
        }

        if (has_next) {
            union { u16 us[8]; uint4 v; } p0, p1;
            p0.us[0] = f2bf(nf0.x); p0.us[1] = f2bf(nf0.y); p0.us[2] = f2bf(nf0.z); p0.us[3] = f2bf(nf0.w);
            p0.us[4] = f2bf(nf1.x); p0.us[5] = f2bf(nf1.y); p0.us[6] = f2bf(nf1.z); p0.us[7] = f2bf(nf1.w);
            p1.us[0] = f2bf(nf2.x); p1.us[1] = f2bf(nf2.y); p1.us[2] = f2bf(nf2.z); p1.us[3] = f2bf(nf2.w);
            p1.us[4] = f2bf(nf3.x); p1.us[5] = f2bf(nf3.y); p1.us[6] = f2bf(nf3.z); p1.us[7] = f2bf(nf3.w);
            u16* sAn = (u16*)(smem + nxt_b * 9216);
            *(uint4*)(sAn + sAwOff) = p0.v;
            *(uint4*)(sAn + sAwOff + 8) = p1.v;
        }
        __syncthreads();   // drains B DMA (vmcnt) + A ds_write (lgkm) for t+1
    }

    // epilogue: bias, LN stats from registers, normalize, write bf16
    float biasv[4], gvv[4], bevv[4];
    #pragma unroll
    for (int ni = 0; ni < 4; ++ni) {
        int col = wv * 64 + ni * 16 + l15;
        biasv[ni] = bias[col]; gvv[ni] = gg[col]; bevv[ni] = be[col];
    }
    #pragma unroll
    for (int mi = 0; mi < 4; ++mi)
        #pragma unroll
        for (int ni = 0; ni < 4; ++ni)
            #pragma unroll
            for (int r = 0; r < 4; ++r) acc[mi][ni][r] += biasv[ni];
    #pragma unroll
    for (int mi = 0; mi < 4; ++mi) {
        #pragma unroll
        for (int r = 0; r < 4; ++r) {
            float s = 0.f, qq = 0.f;
            #pragma unroll
            for (int ni = 0; ni < 4; ++ni) { float x = acc[mi][ni][r]; s += x; qq += x * x; }
            #pragma unroll
            for (int m = 1; m < 16; m <<= 1) { s += __shfl_xor(s, m, 64); qq += __shfl_xor(qq, m, 64); }
            if (l15 == 0) { int rho = mi * 16 + q * 4 + r; redS[rho * 4 + wv] = s; redQ[rho * 4 + wv] = qq; }
        }
    }
    __syncthreads();
    if (t < 64) {
        float s = redS[t * 4] + redS[t * 4 + 1] + redS[t * 4 + 2] + redS[t * 4 + 3];
        float qq = redQ[t * 4] + redQ[t * 4 + 1] + redQ[t * 4 + 2] + redQ[t * 4 + 3];
        float mean = s * (1.f / 256.f);
        float var = qq * (1.f / 256.f) - mean * mean;
        mvS[t * 2] = mean; mvS[t * 2 + 1] = rsqrtf(var + 1e-5f);
    }
    __syncthreads();
    #pragma unroll
    for (int mi = 0; mi < 4; ++mi) {
        #pragma unroll
        for (int r = 0; r < 4; ++r) {
            int rho = mi * 16 + q * 4 + r;
            float mean = mvS[rho * 2], rstd = mvS[rho * 2 + 1];
            #pragma unroll
            for (int ni = 0; ni < 4; ++ni) {
                int col = wv * 64 + ni * 16 + l15;
                float x = (acc[mi][ni][r] - mean) * rstd * gvv[ni] + bevv[ni];
                sC[rho * 256 + col] = f2bf(x);
            }
        }
    }
    __syncthreads();
    u16* outp = stack + (size_t)m0 * 768 + slot * 256;
    #pragma unroll
    for (int it = 0; it < 8; ++it) {
        int idx = t + it * 256;
        int row = idx >> 5, c = idx & 31;
        uint4 v = *(const uint4*)(sC + row * 256 + c * 8);
        *(uint4*)(outp + (size_t)row * 768 + c * 8) = v;
    }
}

// ------------------------------------------------------ K2: qkv = stack@in_w.T
// R3 variant verbatim (best measured e2e component). M=49152, K=256, N=768.
// BM=128, BN=128, 4 waves in 2x2. 3-buffer depth-2 counted-vmcnt pipeline.
__global__ __launch_bounds__(256, 3) void gemm_qkv(const u16* stack, const u16* W, const float* in_b,
                                                   u16* qkv) {
    // buf k @ k*16384: A 8KB + B 8KB (512x16B chunks each, XOR-swizzled)
    __shared__ alignas(16) char smem[49152];
    u16* sC = (u16*)smem;            // epilogue [128][128] overlay

    int t = threadIdx.x, wv = t >> 6, ln = t & 63, q = ln >> 4, l15 = ln & 15;
    int n0 = blockIdx.x * 128, m0 = blockIdx.y * 128;
    int wr = wv >> 1, wc = wv & 1;

    fx4 zero = {0.f, 0.f, 0.f, 0.f};
    fx4 acc[4][4];
    #pragma unroll
    for (int mi = 0; mi < 4; ++mi)
        #pragma unroll
        for (int ni = 0; ni < 4; ++ni) acc[mi][ni] = zero;

    int sR[2], sKc[2];
    #pragma unroll
    for (int i = 0; i < 2; ++i) {
        int d = wv * 128 + i * 64 + ln;
        sR[i] = d >> 2;
        sKc[i] = (d & 3) ^ ((sR[i] >> 1) & 3);
    }

#define QK_ISSUE(ktile, bufoff)                                                         \
    {                                                                                   \
        char* bA_ = smem + (bufoff);                                                    \
        char* bB_ = bA_ + 8192;                                                         \
        _Pragma("unroll")                                                               \
        for (int i_ = 0; i_ < 2; ++i_) {                                                \
            gld16(bA_ + (wv * 128 + i_ * 64) * 16,                                      \
                  stack + (size_t)(m0 + sR[i_]) * 256 + (ktile) * 32 + sKc[i_] * 8);    \
            gld16(bB_ + (wv * 128 + i_ * 64) * 16,                                      \
                  W + (size_t)(n0 + sR[i_]) * 256 + (ktile) * 32 + sKc[i_] * 8);        \
        }                                                                               \
    }

    QK_ISSUE(0, 0);
    QK_ISSUE(1, 16384);
    int cb = 0;
    for (int kt = 0; kt < 8; ++kt) {
        if (kt < 7) { WAIT_VM(4); } else { WAIT_VM(0); }
        __builtin_amdgcn_sched_barrier(0);
        __builtin_amdgcn_s_barrier();
        __builtin_amdgcn_sched_barrier(0);
        int nb = cb + 2; if (nb >= 3) nb -= 3;
        if (kt + 2 < 8) QK_ISSUE(kt + 2, nb * 16384);

        const u16* sAc = (const u16*)(smem + cb * 16384);
        const u16* sBc = (const u16*)(smem + cb * 16384 + 8192);
        bf16x8 af[4], bfr[4];
        #pragma unroll
        for (int mi = 0; mi < 4; ++mi) {
            int r = wr * 64 + mi * 16 + l15;
            int ch = r * 4 + (q ^ ((r >> 1) & 3));
            af[mi] = *(const bf16x8*)(sAc + ch * 8);
        }
        #pragma unroll
        for (int ni = 0; ni < 4; ++ni) {
            int n = wc * 64 + ni * 16 + l15;
            int ch = n * 4 + (q ^ ((n >> 1) & 3));
            bfr[ni] = *(const bf16x8*)(sBc + ch * 8);
        }
        __builtin_amdgcn_s_setprio(1);
        #pragma unroll
        for (int mi = 0; mi < 4; ++mi)
            #pragma unroll
            for (int ni = 0; ni < 4; ++ni)
                acc[mi][ni] = MFMA_BF16(af[mi], bfr[ni], acc[mi][ni]);
        __builtin_amdgcn_s_setprio(0);
        cb += 1; if (cb >= 3) cb -= 3;
    }
#undef QK_ISSUE
    __syncthreads();   // all waves done reading bufs before sC overlay

    float biasv[4];
    #pragma unroll
    for (int ni = 0; ni < 4; ++ni) biasv[ni] = in_b[n0 + wc * 64 + ni * 16 + l15];
    #pragma unroll
    for (int mi = 0; mi < 4; ++mi)
        #pragma unroll
        for (int ni = 0; ni < 4; ++ni)
            #pragma unroll
            for (int r = 0; r < 4; ++r) {
                int rl = wr * 64 + mi * 16 + q * 4 + r;
                int cl = wc * 64 + ni * 16 + l15;
                sC[rl * 128 + cl] = f2bf(acc[mi][ni][r] + biasv[ni]);
            }
    __syncthreads();
    #pragma unroll
    for (int it = 0; it < 8; ++it) {
        int idx = t + it * 256;
        int row = idx >> 4, c = idx & 15;
        uint4 v = *(const uint4*)(sC + row * 128 + c * 8);
        *(uint4*)(qkv + (size_t)(m0 + row) * 768 + n0 + c * 8) = v;
    }
}

// ------------------------------------------------------------- K3: attention
// 8 b's per block. qkv row per (b,i): [q(256)|k(256)|v(256)].
__global__ __launch_bounds__(256) void attn_k(const u16* qkv, u16* ctx) {
    __shared__ alignas(16) char smem[38016];
    u16* qs = (u16*)smem;                 // 8*2304 bf16
    float* sS = (float*)(smem + 36864);   // 288 scores/probs: [b][h][i][j]

    int t = threadIdx.x, wv = t >> 6, ln = t & 63;
    size_t base = (size_t)blockIdx.x * 8 * 2304;
    #pragma unroll
    for (int i = 0; i < 9; ++i) {
        int d = wv * 576 + i * 64;
        gld16((char*)smem + (size_t)d * 16, qkv + base + (size_t)(d + ln) * 8);
    }
    __syncthreads();
    // scores: 288 items = 8b*4h*9(i,j)
    #pragma unroll
    for (int it = 0; it < 2; ++it) {
        int idx = t + it * 256;
        if (idx < 288) {
            int b = idx / 36, rem = idx % 36, h = rem / 9, pp = rem % 9, i = pp / 3, j = pp % 3;
            const u16* qp = qs + b * 2304 + i * 768 + h * 64;
            const u16* kp = qs + b * 2304 + j * 768 + 256 + h * 64;
            float acc = 0.f;
            #pragma unroll
            for (int c = 0; c < 8; ++c) {
                uint4 qa = *(const uint4*)(qp + c * 8);
                uint4 ka = *(const uint4*)(kp + c * 8);
                acc += bfpair_dot(qa.x, ka.x) + bfpair_dot(qa.y, ka.y) +
                       bfpair_dot(qa.z, ka.z) + bfpair_dot(qa.w, ka.w);
            }
            sS[idx] = acc * 0.125f;  // /sqrt(64)
        }
    }
    __syncthreads();
    if (t < 96) {  // softmax over j, t = b*12 + h*3 + i
        int b3 = t * 3;
        float s0 = sS[b3], s1 = sS[b3 + 1], s2 = sS[b3 + 2];
        float m = fmaxf(s0, fmaxf(s1, s2));
        float e0 = __expf(s0 - m), e1 = __expf(s1 - m), e2 = __expf(s2 - m);
        float inv = 1.f / (e0 + e1 + e2);
        sS[b3] = e0 * inv; sS[b3 + 1] = e1 * inv; sS[b3 + 2] = e2 * inv;
    }
    __syncthreads();
    // ctx: 768 items = 8b * 3i * 32 chunks-of-8
    #pragma unroll
    for (int it = 0; it < 3; ++it) {
        int idx = t + it * 256;
        int b = idx / 96, rem = idx % 96, i = rem / 32, c = rem & 31, h = c >> 3;
        int pbase = b * 36 + h * 9 + i * 3;
        float o[8];
        #pragma unroll
        for (int e = 0; e < 8; ++e) o[e] = 0.f;
        #pragma unroll
        for (int j = 0; j < 3; ++j) {
            float p = sS[pbase + j];
            uint4 va = *(const uint4*)(qs + b * 2304 + j * 768 + 512 + c * 8);
            unsigned uu[4] = {va.x, va.y, va.z, va.w};
            #pragma unroll
            for (int pr = 0; pr < 4; ++pr) {
                union { unsigned u; float f; } lo, hi;
                lo.u = uu[pr] << 16; hi.u = uu[pr] & 0xffff0000u;
                o[2 * pr]     += p * lo.f;
                o[2 * pr + 1] += p * hi.f;
            }
        }
        union { u16 us[8]; uint4 v; } pk;
        #pragma unroll
        for (int e = 0; e < 8; ++e) pk.us[e] = f2bf(o[e]);
        *(uint4*)(ctx + (size_t)(blockIdx.x * 8 + b) * 768 + i * 256 + c * 8) = pk.v;
    }
}

// -------------------- K4: out-proj + residual + LN + gating MLP + fused output
// R3 variant verbatim. BM=48 (16 b's), BN=256, K=256.
__global__ __launch_bounds__(256) void outproj_k(
    const u16* ctx, const u16* W, const float* out_b, const u16* stack,
    const float* gn, const float* gb, const u16* g1w, const float* g1b,
    const float* g2w, const float* g2b, float* outF, float* outG) {
    __shared__ alignas(16) char smem[40960];
    u16* r1 = (u16*)smem;                         // 24576B
    u16* sB = (u16*)(smem + 24576);               // 16384B (k-loop)
    float* redS = (float*)(smem + 24576);         // 48*4
    float* redQ = redS + 192;
    float* mvS = redQ + 192;                      // 48*2
    float* h1S = (float*)(smem + 26624);          // [16][64]
    float* lgS = (float*)(smem + 30720);          // 48 logits
    float* gateS = lgS + 48;                      // 48 gates

    int t = threadIdx.x, wv = t >> 6, ln = t & 63, q = ln >> 4, l15 = ln & 15;
    int gr0 = blockIdx.x * 48, b0 = blockIdx.x * 16;

    // stage full ctx tile [48][256] once, chunk pos p holds k-chunk p^(row&7)
    #pragma unroll
    for (int i = 0; i < 6; ++i) {
        int d = wv * 384 + i * 64 + ln;
        int row = d >> 5, p = d & 31;
        int kc = p ^ (row & 7);
        gld16((char*)r1 + (wv * 384 + i * 64) * 16, ctx + (size_t)(gr0 + row) * 256 + kc * 8);
    }
    __syncthreads();

    fx4 zero = {0.f, 0.f, 0.f, 0.f};
    fx4 acc[3][4];
    #pragma unroll
    for (int mi = 0; mi < 3; ++mi)
        #pragma unroll
        for (int ni = 0; ni < 4; ++ni) acc[mi][ni] = zero;

    for (int kt = 0; kt < 8; ++kt) {
        #pragma unroll
        for (int i = 0; i < 4; ++i) {
            int d = wv * 256 + i * 64 + ln;
            int n = d >> 2, p = d & 3;
            int kc = p ^ ((n >> 1) & 3);
            gld16((char*)sB + (wv * 256 + i * 64) * 16, W + (size_t)n * 256 + kt * 32 + kc * 8);
        }
        __syncthreads();
        bf16x8 af[3], bfr[4];
        #pragma unroll
        for (int mi = 0; mi < 3; ++mi) {
            int row = mi * 16 + l15;
            int ch = row * 32 + ((kt * 4 + q) ^ (row & 7));
            af[mi] = *(const bf16x8*)(r1 + ch * 8);
        }
        #pragma unroll
        for (int ni = 0; ni < 4; ++ni) {
            int n = wv * 64 + ni * 16 + l15;
            int ch = n * 4 + (q ^ ((n >> 1) & 3));
            bfr[ni] = *(const bf16x8*)(sB + ch * 8);
        }
        #pragma unroll
        for (int mi = 0; mi < 3; ++mi)
            #pragma unroll
            for (int ni = 0; ni < 4; ++ni)
                acc[mi][ni] = MFMA_BF16(af[mi], bfr[ni], acc[mi][ni]);
        __syncthreads();
    }

    // stage stack tile [48][256] (contiguous in global) into r1
    #pragma unroll
    for (int i = 0; i < 6; ++i) {
        int d = wv * 384 + i * 64 + ln;
        gld16((char*)r1 + (wv * 384 + i * 64) * 16, stack + (size_t)gr0 * 256 + (size_t)d * 8);
    }
    __syncthreads();

    float obv[4], gnv[4], gbv[4];
    #pragma unroll
    for (int ni = 0; ni < 4; ++ni) {
        int col = wv * 64 + ni * 16 + l15;
        obv[ni] = out_b[col]; gnv[ni] = gn[col]; gbv[ni] = gb[col];
    }
    #pragma unroll
    for (int mi = 0; mi < 3; ++mi)
        #pragma unroll
        for (int ni = 0; ni < 4; ++ni)
            #pragma unroll
            for (int r = 0; r < 4; ++r) {
                int rho = mi * 16 + q * 4 + r;
                int col = wv * 64 + ni * 16 + l15;
                acc[mi][ni][r] += obv[ni] + bf2f(r1[rho * 256 + col]);
            }
    // LN stats
    #pragma unroll
    for (int mi = 0; mi < 3; ++mi) {
        #pragma unroll
        for (int r = 0; r < 4; ++r) {
            float s = 0.f, qq = 0.f;
            #pragma unroll
            for (int ni = 0; ni < 4; ++ni) { float x = acc[mi][ni][r]; s += x; qq += x * x; }
            #pragma unroll
            for (int m = 1; m < 16; m <<= 1) { s += __shfl_xor(s, m, 64); qq += __shfl_xor(qq, m, 64); }
            if (l15 == 0) { int rho = mi * 16 + q * 4 + r; redS[rho * 4 + wv] = s; redQ[rho * 4 + wv] = qq; }
        }
    }
    __syncthreads();
    if (t < 48) {
        float s = redS[t * 4] + redS[t * 4 + 1] + redS[t * 4 + 2] + redS[t * 4 + 3];
        float qq = redQ[t * 4] + redQ[t * 4 + 1] + redQ[t * 4 + 2] + redQ[t * 4 + 3];
        float mean = s * (1.f / 256.f);
        float var = qq * (1.f / 256.f) - mean * mean;
        mvS[t * 2] = mean; mvS[t * 2 + 1] = rsqrtf(var + 1e-5f);
    }
    __syncthreads();
    // normalize -> rowBuf (r1, swizzled as [16 b][96 chunks], chunk = bl*96 + (kidx^(bl&7)))
    #pragma unroll
    for (int mi = 0; mi < 3; ++mi) {
        #pragma unroll
        for (int r = 0; r < 4; ++r) {
            int rho = mi * 16 + q * 4 + r;
            float mean = mvS[rho * 2], rstd = mvS[rho * 2 + 1];
            int bl = rho / 3, sl = rho - bl * 3;
            #pragma unroll
            for (int ni = 0; ni < 4; ++ni) {
                int col = wv * 64 + ni * 16 + l15;
                float x = (acc[mi][ni][r] - mean) * rstd * gnv[ni] + gbv[ni];
                int k = sl * 256 + col;
                int kidx = k >> 3, wn = k & 7;
                r1[(bl * 96 + (kidx ^ (bl & 7))) * 8 + wn] = f2bf(x);
            }
        }
    }
    __syncthreads();
    // gating MFMA: h1[16 b][64] = attended_flat(16x768) @ g1w.T ; wave wv owns cols wv*16..+15
    fx4 ag = zero;
    for (int kt = 0; kt < 24; ++kt) {
        int bl = l15;
        int kidx = kt * 4 + q;
        bf16x8 afr = *(const bf16x8*)(r1 + (bl * 96 + (kidx ^ (bl & 7))) * 8);
        int n = wv * 16 + l15;
        bf16x8 bfr2 = *(const bf16x8*)(g1w + (size_t)n * 768 + kt * 32 + q * 8);
        ag = MFMA_BF16(afr, bfr2, ag);
    }
    #pragma unroll
    for (int r = 0; r < 4; ++r) {
        int bl = q * 4 + r, n = wv * 16 + l15;
        float x = ag[r] + g1b[n];
        h1S[bl * 64 + n] = 0.5f * x * (1.f + erff(x * 0.70710678118f));
    }
    __syncthreads();
    if (t < 48) {  // logits: t = bl*3 + s
        int bl = t / 3, s = t - bl * 3;
        float a = g2b[s];
        #pragma unroll
        for (int k = 0; k < 64; ++k) a += h1S[bl * 64 + k] * g2w[s * 64 + k];
        lgS[t] = a;
    }
    __syncthreads();
    if (t < 48) {
        int bl = t / 3, s = t - bl * 3;
        float l0 = lgS[bl * 3], l1 = lgS[bl * 3 + 1], l2 = lgS[bl * 3 + 2];
        float m = fmaxf(l0, fmaxf(l1, l2));
        float e0 = __expf(l0 - m), e1 = __expf(l1 - m), e2 = __expf(l2 - m);
        float inv = 1.f / (e0 + e1 + e2);
        float gsel = ((s == 0) ? e0 : (s == 1) ? e1 : e2) * inv;
        gateS[t] = gsel;
        outG[(size_t)(b0 + bl) * 3 + s] = gsel;
    }
    __syncthreads();
    // fused = sum_s gate[s] * attended[s]
    #pragma unroll
    for (int it = 0; it < 2; ++it) {
        int idx = t + it * 256;
        int b = idx >> 5, c = idx & 31;
        float g0 = gateS[b * 3], g1 = gateS[b * 3 + 1], g2 = gateS[b * 3 + 2];
        float o[8];
        #pragma unroll
        for (int e = 0; e < 8; ++e) o[e] = 0.f;
        #pragma unroll
        for (int s = 0; s < 3; ++s) {
            float gw = (s == 0) ? g0 : (s == 1) ? g1 : g2;
            int kidx = s * 32 + c;
            uint4 raw = *(const uint4*)(r1 + (b * 96 + (kidx ^ (b & 7))) * 8);
            unsigned uu[4] = {raw.x, raw.y, raw.z, raw.w};
            #pragma unroll
            for (int pr = 0; pr < 4; ++pr) {
                union { unsigned u; float f; } lo, hi;
                lo.u = uu[pr] << 16; hi.u = uu[pr] & 0xffff0000u;
                o[2 * pr]     += gw * lo.f;
                o[2 * pr + 1] += gw * hi.f;
            }
        }
        float* op = outF + (size_t)(b0 + b) * 256 + c * 8;
        float4 v0; v0.x = o[0]; v0.y = o[1]; v0.z = o[2]; v0.w = o[3];
        float4 v1; v1.x = o[4]; v1.y = o[5]; v1.z = o[6]; v1.w = o[7];
        *(float4*)op = v0;
        *(float4*)(op + 4) = v1;
    }
}

extern "C" void kernel_launch(void* const* d_in, const int* in_sizes, int n_in,
                              void* d_out, int out_size, void* d_ws, size_t ws_size,
                              hipStream_t stream) {
    (void)in_sizes; (void)n_in; (void)out_size; (void)ws_size;
    const float* fv   = (const float*)d_in[0];
    const float* fs   = (const float*)d_in[1];
    const float* fc   = (const float*)d_in[2];
    const float* Wv   = (const float*)d_in[3];
    const float* bv   = (const float*)d_in[4];
    const float* gv   = (const float*)d_in[5];
    const float* bev  = (const float*)d_in[6];
    const float* Ws   = (const float*)d_in[7];
    const float* bs   = (const float*)d_in[8];
    const float* gs   = (const float*)d_in[9];
    const float* bes  = (const float*)d_in[10];
    const float* Wc   = (const float*)d_in[11];
    const float* bc   = (const float*)d_in[12];
    const float* gc_  = (const float*)d_in[13];
    const float* bec  = (const float*)d_in[14];
    const float* in_w = (const float*)d_in[15];
    const float* in_b = (const float*)d_in[16];
    const float* out_w= (const float*)d_in[17];
    const float* out_b= (const float*)d_in[18];
    const float* gn   = (const float*)d_in[19];
    const float* gb   = (const float*)d_in[20];
    const float* g1w  = (const float*)d_in[21];
    const float* g1b  = (const float*)d_in[22];
    const float* g2w  = (const float*)d_in[23];
    const float* g2b  = (const float*)d_in[24];

    u16* w0    = (u16*)d_ws;
    u16* wWv   = w0;               // 524288
    u16* wWs   = w0 + 524288;      // 262144
    u16* wWc   = w0 + 786432;      // 131072
    u16* wIn   = w0 + 917504;      // 196608
    u16* wOut  = w0 + 1114112;     // 65536
    u16* wG1   = w0 + 1179648;     // 49152
    u16* stack = w0 + 1228800;     // 49152*256
    u16* qkv   = w0 + 13811712;    // 49152*768
    u16* ctx   = w0 + 51560448;    // 49152*256  (total 64143360 u16 = ~128.3 MB)
    float* outF = (float*)d_out;
    float* outG = outF + (size_t)16384 * 256;

    cvt_w<<<4800, 256, 0, stream>>>(Wv, Ws, Wc, in_w, out_w, g1w, w0);
    gemm_ln<<<768, 256, 0, stream>>>(fv, fs, fc, wWv, wWs, wWc,
                                     bv, gv, bev, bs, gs, bes, bc, gc_, bec, stack);
    gemm_qkv<<<dim3(6, 384), 256, 0, stream>>>(stack, wIn, in_b, qkv);
    attn_k<<<2048, 256, 0, stream>>>(qkv, ctx);
    outproj_k<<<1024, 256, 0, stream>>>(ctx, wOut, out_b, stack, gn, gb,
                                        wG1, g1b, g2w, g2b, outF, outG);
}